// Round 9
// baseline (416.730 us; speedup 1.0000x reference)
//
#include <hip/hip_runtime.h>

// ---------------------------------------------------------------------------
// Fused MHA: B=2, T=2048, M=2048, H=16, D=128, causal, qk-centered-RMS-norm,
// half-split rotary, QK_SCALE = 1/D.
// Pipeline: cast/transposes -> QKV GEMM (256^2 8-wave, R4 minimal-sync loop;
// V written tile-transposed) -> norm+rope -> flash attn (QBLK=128: 32 q-rows
// per wave, 1 barrier/tile, gload_lds staging, dbuf) -> out GEMM.
// ---------------------------------------------------------------------------

#define NB 2
#define NT 2048
#define NM 2048
#define NH 16
#define ND 128

typedef __attribute__((ext_vector_type(4))) float f32x4;
typedef __attribute__((ext_vector_type(8))) short bf16x8;
typedef __attribute__((ext_vector_type(4))) short bf16x4;

#define AS1 __attribute__((address_space(1)))
#define AS3 __attribute__((address_space(3)))

__device__ __forceinline__ unsigned short f2bf(float f){
  unsigned int u = __float_as_uint(f);
  u = (u + 0x7fffu + ((u >> 16) & 1u)) >> 16;   // RNE
  return (unsigned short)u;
}
__device__ __forceinline__ float bf2f(short s){
  return __uint_as_float(((unsigned int)(unsigned short)s) << 16);
}
__device__ __forceinline__ float wredsum(float v){
  #pragma unroll
  for (int m = 1; m < 64; m <<= 1) v += __shfl_xor(v, m);
  return v;
}
__device__ __forceinline__ void gload_lds16(const void* g, void* l){
  __builtin_amdgcn_global_load_lds((const AS1 void*)g, (AS3 void*)l, 16, 0, 0);
}

// ---------------- rope cos/sin table: [T][64] each --------------------------
__global__ __launch_bounds__(64) void rope_table_k(float* ctab, float* stab){
  int t = blockIdx.x, i = threadIdx.x;
  float freq = __expf(-(float)i * (9.210340371976184f / 64.0f)); // ln(10000)
  float ang = (float)t * freq;
  ctab[t * 64 + i] = cosf(ang);
  stab[t * 64 + i] = sinf(ang);
}

// ---------------- cast x fp32 -> bf16 --------------------------------------
__global__ __launch_bounds__(256) void cast_x_k(const float* __restrict__ x,
                                                short* __restrict__ xb){
  size_t gid = (size_t)blockIdx.x * 256 + threadIdx.x;
  float4 v = *(const float4*)(x + gid * 4);
  bf16x4 o;
  o[0] = (short)f2bf(v.x); o[1] = (short)f2bf(v.y);
  o[2] = (short)f2bf(v.z); o[3] = (short)f2bf(v.w);
  *(bf16x4*)(xb + gid * 4) = o;
}

// ------------- transpose weights fp32 [K][N] -> bf16 [N][K] ----------------
__global__ __launch_bounds__(256) void transpose_w_k(const float* __restrict__ wq,
                                                     const float* __restrict__ wk,
                                                     const float* __restrict__ wv,
                                                     const float* __restrict__ wo,
                                                     short* __restrict__ wT){
  __shared__ float tl[32][33];
  int z = blockIdx.z;
  const float* src = (z == 0) ? wq : (z == 1) ? wk : (z == 2) ? wv : wo;
  short* dst = wT + (size_t)z * 2048 * 2048;
  int n0 = blockIdx.x * 32, k0 = blockIdx.y * 32;
  int cx = threadIdx.x & 31, ry = threadIdx.x >> 5; // 0..7
  #pragma unroll
  for (int p = 0; p < 4; ++p)
    tl[ry + 8 * p][cx] = src[(size_t)(k0 + ry + 8 * p) * 2048 + n0 + cx];
  __syncthreads();
  #pragma unroll
  for (int p = 0; p < 4; ++p)
    dst[(size_t)(n0 + ry + 8 * p) * 2048 + k0 + cx] =
        (short)f2bf(tl[cx][ry + 8 * p]);
}

// ---------------------------------------------------------------------------
// QKV GEMM: C[4096 x 6144] = A[4096 x 2048] * B^T[6144 x 2048] (bf16)
// 256x256 tile, BK=64, 8 waves, 512 threads, 128 KiB dynamic LDS.
// R4 minimal-sync K-loop. tsel block-uniform. V tiled-transposed.
// ---------------------------------------------------------------------------
#define NKT 32   // 2048 / 64
__global__ __launch_bounds__(512, 2) void gemm256_k(const short* __restrict__ A,
                                                    const short* __restrict__ Bt,
                                                    short* __restrict__ Cq){
  extern __shared__ char lds[];
  const int tid = threadIdx.x;
  const int wid = tid >> 6, lane = tid & 63;
  const int lrow = lane & 15, g8 = lane >> 4;
  const int wm = wid >> 2, wn = wid & 3;
  const int Kdim = 2048;

  int bid = blockIdx.x;
  int s = (bid & 7) * 48 + (bid >> 3);
  const int bx = s & 15;
  const int by = s >> 4;
  const int m0 = bx * 256, n0 = by * 256;

  const int r8 = lane >> 3;
  const int gcol = ((lane & 7) ^ r8) * 8;
  const short* Ab = A  + (size_t)(m0 + wid * 8 + r8) * Kdim + gcol;
  const short* Bb = Bt + (size_t)(n0 + wid * 8 + r8) * Kdim + gcol;

  f32x4 acc[8][4] = {};

  auto STAGE = [&](int c, int kt){
    #pragma unroll
    for (int h = 0; h < 2; ++h)
      #pragma unroll
      for (int l = 0; l < 2; ++l){
        size_t roff = (size_t)(h * 128 + l * 64) * Kdim + kt * 64;
        char* la = lds + c * 32768 + h * 16384 + l * 8192 + wid * 1024;
        gload_lds16(Ab + roff, la);
        gload_lds16(Bb + roff, la + 65536);
      }
  };
  auto ldA = [&](int c, int mi, int kk) -> bf16x8 {
    int row = mi * 16 + lrow;
    int col = (kk * 64 + g8 * 16) ^ ((lrow & 7) << 4);
    return *(const bf16x8*)(lds + c * 32768 + wm * 16384 + row * 128 + col);
  };
  auto ldB = [&](int c, int ni, int kk) -> bf16x8 {
    int row = (wn & 1) * 64 + ni * 16 + lrow;
    int col = (kk * 64 + g8 * 16) ^ ((lrow & 7) << 4);
    return *(const bf16x8*)(lds + 65536 + c * 32768 + (wn >> 1) * 16384 + row * 128 + col);
  };

  STAGE(0, 0);

  for (int kt = 0; kt < NKT; ++kt){
    const int c = kt & 1;
    asm volatile("s_waitcnt vmcnt(0)" ::: "memory");
    __builtin_amdgcn_s_barrier();
    if (kt + 1 < NKT) STAGE(c ^ 1, kt + 1);

    #pragma unroll
    for (int kk = 0; kk < 2; ++kk){
      bf16x8 bfr[4];
      #pragma unroll
      for (int ni = 0; ni < 4; ++ni) bfr[ni] = ldB(c, ni, kk);
      #pragma unroll
      for (int mh = 0; mh < 2; ++mh){
        bf16x8 afr[4];
        #pragma unroll
        for (int mi = 0; mi < 4; ++mi) afr[mi] = ldA(c, mh * 4 + mi, kk);
        #pragma unroll
        for (int mi = 0; mi < 4; ++mi)
          #pragma unroll
          for (int ni = 0; ni < 4; ++ni)
            acc[mh * 4 + mi][ni] = __builtin_amdgcn_mfma_f32_16x16x32_bf16(
                afr[mi], bfr[ni], acc[mh * 4 + mi][ni], 0, 0, 0);
      }
    }
  }

  const int tsel = by >> 3;           // 0=q, 1=k, 2=v (block-uniform)
  short* dst = Cq + (size_t)tsel * (NB * NH * NT * ND);
  if (tsel < 2){
    #pragma unroll
    for (int mi = 0; mi < 8; ++mi){
      int rowb = m0 + wm * 128 + mi * 16 + g8 * 4;
      #pragma unroll
      for (int ni = 0; ni < 4; ++ni){
        int col = n0 + wn * 64 + ni * 16 + lrow;
        int hd = col & 2047;
        int hh = hd >> 7, d = hd & 127;
        f32x4 a = acc[mi][ni];
        #pragma unroll
        for (int r = 0; r < 4; ++r){
          int bt = rowb + r;
          int b = bt >> 11, t = bt & 2047;
          dst[(((size_t)(b * NH + hh)) * NT + t) * ND + d] = (short)f2bf(a[r]);
        }
      }
    }
  } else {
    #pragma unroll
    for (int mi = 0; mi < 8; ++mi){
      int rowb = m0 + wm * 128 + mi * 16 + g8 * 4;
      int b = rowb >> 11, t0 = rowb & 2047;
      int jb = t0 >> 6, toff = t0 & 63;
      #pragma unroll
      for (int ni = 0; ni < 4; ++ni){
        int col = n0 + wn * 64 + ni * 16 + lrow;
        int hd = col & 2047;
        int hh = hd >> 7, d = hd & 127;
        f32x4 a = acc[mi][ni];
        bf16x4 w4;
        #pragma unroll
        for (int r = 0; r < 4; ++r) w4[r] = (short)f2bf(a[r]);
        *(bf16x4*)&dst[(((size_t)(b * NH + hh) * 32 + jb) * ND + d) * 64 + toff] = w4;
      }
    }
  }
}

// ---------------- out-proj GEMM (128^2, double-buffered, 1-barrier) --------
__global__ __launch_bounds__(256) void gemm_bt_k(const short* __restrict__ A,
                                                 const short* __restrict__ Bt,
                                                 float* __restrict__ Cout,
                                                 int Kdim){
  __shared__ short As[2][128 * 32];
  __shared__ short Bs[2][128 * 32];
  const int tid = threadIdx.x;
  const int wid = tid >> 6, lane = tid & 63;
  const int lrow = lane & 15, g8 = lane >> 4;
  const int wm = wid >> 1, wn = wid & 1;
  const int m0 = blockIdx.x * 128, n0 = blockIdx.y * 128;
  f32x4 acc[4][4] = {};
  const int srow = lane >> 2;
  const int skcol = (lane & 3) * 8;

  auto STAGE = [&](int c, int kt){
    #pragma unroll
    for (int i = 0; i < 2; ++i){
      int inst = wid * 2 + i;
      int r = inst * 16 + srow;
      const short* sa = A  + (size_t)(m0 + r) * Kdim + kt + skcol;
      const short* sb = Bt + (size_t)(n0 + r) * Kdim + kt + skcol;
      gload_lds16(sa, (char*)As[c] + inst * 1024);
      gload_lds16(sb, (char*)Bs[c] + inst * 1024);
    }
  };

  STAGE(0, 0);
  const int nkt = Kdim >> 5;
  for (int it = 0; it < nkt; ++it){
    const int c = it & 1;
    asm volatile("s_waitcnt vmcnt(0)" ::: "memory");
    __builtin_amdgcn_s_barrier();
    if (it + 1 < nkt) STAGE(c ^ 1, (it + 1) << 5);

    bf16x8 af[4], bfv[4];
    #pragma unroll
    for (int mi = 0; mi < 4; ++mi)
      af[mi] = *(const bf16x8*)&As[c][(wm * 64 + mi * 16 + lrow) * 32 + g8 * 8];
    #pragma unroll
    for (int ni = 0; ni < 4; ++ni)
      bfv[ni] = *(const bf16x8*)&Bs[c][(wn * 64 + ni * 16 + lrow) * 32 + g8 * 8];
    #pragma unroll
    for (int mi = 0; mi < 4; ++mi)
      #pragma unroll
      for (int ni = 0; ni < 4; ++ni)
        acc[mi][ni] = __builtin_amdgcn_mfma_f32_16x16x32_bf16(
            af[mi], bfv[ni], acc[mi][ni], 0, 0, 0);
  }

  #pragma unroll
  for (int mi = 0; mi < 4; ++mi){
    int rowb = m0 + wm * 64 + mi * 16 + g8 * 4;
    #pragma unroll
    for (int ni = 0; ni < 4; ++ni){
      int col = n0 + wn * 64 + ni * 16 + lrow;
      f32x4 a = acc[mi][ni];
      #pragma unroll
      for (int r = 0; r < 4; ++r)
        Cout[(size_t)(rowb + r) * 2048 + col] = a[r];
    }
  }
}

// -------------- centered RMS norm + rotary (q and k) -----------------------
__global__ __launch_bounds__(256) void norm_rope_k(const short* __restrict__ qkv,
                                                   short* __restrict__ outp,
                                                   const float* __restrict__ gq,
                                                   const float* __restrict__ bq,
                                                   const float* __restrict__ gk,
                                                   const float* __restrict__ bk,
                                                   const float* __restrict__ ctab,
                                                   const float* __restrict__ stab){
  int which = blockIdx.y;
  const short* src = qkv + (size_t)which * (NB * NH * NT * ND);
  short* dst = outp + (size_t)which * (NB * NH * NT * ND);
  const float* g = which ? gk : gq;
  const float* bb = which ? bk : bq;
  int wid = threadIdx.x >> 6, lane = threadIdx.x & 63;
  size_t row = (size_t)blockIdx.x * 4 + wid;  // over B*H*T
  int h = (int)((row >> 11) & 15);
  int t = (int)(row & 2047);
  const short* rp = src + row * ND;
  float v0 = bf2f(rp[lane]), v1 = bf2f(rp[lane + 64]);
  float mean = wredsum(v0 + v1) * (1.0f / 128.0f);
  float c0 = v0 - mean, c1 = v1 - mean;
  float ms = wredsum(c0 * c0 + c1 * c1) * (1.0f / 128.0f);
  float rstd = rsqrtf(ms + 1e-6f);
  float n0 = c0 * rstd * (1.0f + g[h * ND + lane]) + bb[h * ND + lane];
  float n1 = c1 * rstd * (1.0f + g[h * ND + lane + 64]) + bb[h * ND + lane + 64];
  float co = ctab[t * 64 + lane], si = stab[t * 64 + lane];
  short* wp = dst + row * ND;
  wp[lane]      = (short)f2bf(n0 * co - n1 * si);
  wp[lane + 64] = (short)f2bf(n0 * si + n1 * co);
}

// ---------------- flash attention, causal, QBLK=128 ------------------------
// Each wave owns TWO 16-row q-blocks (A: rows sx*128+wid*16.., B: +64).
// KV tile 64 staged via global_load_lds (pre-swizzled source), dbuf,
// ONE barrier per tile. Row-block A skips the final (fully-masked) tile.
// LDS: K[2][16KB] | V^T[2][16KB] | Ps[4 waves][4KB] = 80 KiB dynamic.
__global__ __launch_bounds__(256) void attn_k(const short* __restrict__ qn,
                                              const short* __restrict__ kn,
                                              const short* __restrict__ vt,
                                              short* __restrict__ ob){
  extern __shared__ char lds[];
  const int tid = threadIdx.x;
  const int wid = tid >> 6, lane = tid & 63;
  const int lrow = lane & 15, g8 = lane >> 4;
  const int bh = blockIdx.y;
  const int b = bh >> 4, h = bh & 15;
  const size_t base = (size_t)bh * NT * ND;
  char* PwA = lds + 65536 + wid * 4096;
  char* PwB = PwA + 2048;

  auto STAGE = [&](int cb, int jb){
    #pragma unroll
    for (int i = 0; i < 4; ++i){
      int r0 = wid * 16 + i * 4;
      int r = r0 + (lane >> 4);
      int g = lane & 15;
      gload_lds16(kn + base + (size_t)(jb * 64 + r) * ND + ((g ^ (r & 7)) << 3),
                  lds + cb * 16384 + r0 * 256);
    }
    #pragma unroll
    for (int i = 0; i < 4; ++i){
      int d0 = wid * 32 + i * 8;
      int d = d0 + (lane >> 3);
      int g = lane & 7;
      gload_lds16(vt + base + (size_t)jb * 8192 + d * 64 + ((g ^ (d & 7)) << 3),
                  lds + 32768 + cb * 16384 + d0 * 128);
    }
  };

  // QK^T + softmax + P-write for one 16-row block
  auto QKSM = [&](const bf16x8* qf, int tq, float& m, float& lsum, f32x4* O,
                  char* Pw, const char* Kb, int jb){
    f32x4 st[4] = {};
    __builtin_amdgcn_s_setprio(1);
    #pragma unroll
    for (int dc = 0; dc < 4; ++dc)
      #pragma unroll
      for (int js = 0; js < 4; ++js){
        int jl = js * 16 + lrow;
        bf16x8 kf = *(const bf16x8*)(Kb + jl * 256 +
                      (((dc * 4 + g8) ^ (jl & 7)) << 4));
        st[js] = __builtin_amdgcn_mfma_f32_16x16x32_bf16(kf, qf[dc], st[js], 0, 0, 0);
      }
    __builtin_amdgcn_s_setprio(0);
    float mx = -3e38f;
    #pragma unroll
    for (int js = 0; js < 4; ++js)
      #pragma unroll
      for (int r = 0; r < 4; ++r){
        float s = st[js][r] * (1.0f / 128.0f);
        int j = jb * 64 + js * 16 + g8 * 4 + r;
        if (j > tq) s = -3e38f;
        st[js][r] = s;
        mx = fmaxf(mx, s);
      }
    mx = fmaxf(mx, __shfl_xor(mx, 16));
    mx = fmaxf(mx, __shfl_xor(mx, 32));
    float mnew = fmaxf(m, mx);
    float fac = __expf(m - mnew);
    m = mnew;
    lsum *= fac;
    #pragma unroll
    for (int dcb = 0; dcb < 8; ++dcb) O[dcb] *= fac;
    float ps = 0.0f;
    #pragma unroll
    for (int js = 0; js < 4; ++js)
      #pragma unroll
      for (int r = 0; r < 4; ++r){
        float p = __expf(st[js][r] - mnew);
        ps += p;
        int jl = js * 16 + g8 * 4 + r;
        *(short*)(Pw + lrow * 128 + ((jl * 2) ^ ((lrow & 7) << 4))) = (short)f2bf(p);
      }
    ps += __shfl_xor(ps, 16);
    ps += __shfl_xor(ps, 32);
    lsum += ps;
  };
  auto PV = [&](f32x4* O, const char* Pw, const char* Vb){
    #pragma unroll
    for (int j32 = 0; j32 < 2; ++j32){
      bf16x8 pf = *(const bf16x8*)(Pw + lrow * 128 +
                    ((j32 * 64 + g8 * 16) ^ ((lrow & 7) << 4)));
      #pragma unroll
      for (int dcb = 0; dcb < 8; ++dcb){
        int d = dcb * 16 + lrow;
        bf16x8 vf = *(const bf16x8*)(Vb + d * 128 +
                      (((j32 * 4 + g8) ^ (d & 7)) << 4));
        O[dcb] = __builtin_amdgcn_mfma_f32_16x16x32_bf16(vf, pf, O[dcb], 0, 0, 0);
      }
    }
  };

  for (int pass = 0; pass < 2; ++pass){
    const int sx = pass ? (15 - (int)blockIdx.x) : (int)blockIdx.x;
    const int tqA = sx * 128 + wid * 16 + lrow;
    const int tqB = tqA + 64;
    bf16x8 qfA[4], qfB[4];
    #pragma unroll
    for (int dc = 0; dc < 4; ++dc){
      qfA[dc] = *(const bf16x8*)(qn + base + (size_t)tqA * ND + dc * 32 + g8 * 8);
      qfB[dc] = *(const bf16x8*)(qn + base + (size_t)tqB * ND + dc * 32 + g8 * 8);
    }
    f32x4 OA[8] = {}, OB[8] = {};
    float mA = -3e38f, lA = 0.0f, mB = -3e38f, lB = 0.0f;
    const int ntiles = 2 * sx + 2;

    __syncthreads();             // protect LDS from previous pass reads
    STAGE(0, 0);

    for (int jb = 0; jb < ntiles; ++jb){
      const int cb = jb & 1;
      asm volatile("s_waitcnt vmcnt(0)" ::: "memory");
      __builtin_amdgcn_s_barrier();              // tile jb resident
      if (jb + 1 < ntiles) STAGE(cb ^ 1, jb + 1);
      const char* Kb = lds + cb * 16384;
      const char* Vb = lds + 32768 + cb * 16384;
      const bool Aact = (jb + 1 < ntiles);       // A's last tile is ntiles-2

      if (Aact) QKSM(qfA, tqA, mA, lA, OA, PwA, Kb, jb);
      QKSM(qfB, tqB, mB, lB, OB, PwB, Kb, jb);
      asm volatile("s_waitcnt lgkmcnt(0)" ::: "memory");
      __builtin_amdgcn_s_setprio(1);
      if (Aact) PV(OA, PwA, Vb);
      PV(OB, PwB, Vb);
      __builtin_amdgcn_s_setprio(0);
    }
    // ---- write both row-blocks ----
    float invA = 1.0f / lA, invB = 1.0f / lB;
    #pragma unroll
    for (int dcb = 0; dcb < 8; ++dcb){
      bf16x4 wA, wB;
      #pragma unroll
      for (int r = 0; r < 4; ++r){
        wA[r] = (short)f2bf(OA[dcb][r] * invA);
        wB[r] = (short)f2bf(OB[dcb][r] * invB);
      }
      *(bf16x4*)(ob + ((size_t)(b * NT + tqA)) * (NH * ND) + h * ND + dcb * 16 + g8 * 4) = wA;
      *(bf16x4*)(ob + ((size_t)(b * NT + tqB)) * (NH * ND) + h * ND + dcb * 16 + g8 * 4) = wB;
    }
  }
}

// ---------------------------------------------------------------------------
extern "C" void kernel_launch(void* const* d_in, const int* in_sizes, int n_in,
                              void* d_out, int out_size, void* d_ws, size_t ws_size,
                              hipStream_t stream){
  const float* x  = (const float*)d_in[0];
  const float* wq = (const float*)d_in[1];
  const float* wk = (const float*)d_in[2];
  const float* wv = (const float*)d_in[3];
  const float* wo = (const float*)d_in[4];
  const float* gq = (const float*)d_in[5];
  const float* bq = (const float*)d_in[6];
  const float* gk = (const float*)d_in[7];
  const float* bk = (const float*)d_in[8];

  char* ws = (char*)d_ws;
  short* xb   = (short*)(ws);                      // 16,777,216 B
  short* wT   = (short*)(ws + 16777216);           // 33,554,432 B (q,k,v,o ^T)
  short* qkvb = (short*)(ws + 50331648);           // 50,331,648 B (q|k|v^T bf16)
  short* qkn  = (short*)(ws + 100663296);          // 33,554,432 B (qn|kn)
  short* ob   = (short*)(ws + 134217728);          // 16,777,216 B
  float* ctab = (float*)(ws + 150994944);          // 524,288 B
  float* stab = (float*)(ws + 151519232);          // 524,288 B

  (void)hipFuncSetAttribute((const void*)gemm256_k,
                            hipFuncAttributeMaxDynamicSharedMemorySize, 131072);
  (void)hipFuncSetAttribute((const void*)attn_k,
                            hipFuncAttributeMaxDynamicSharedMemorySize, 81920);

  rope_table_k<<<dim3(2048), dim3(64), 0, stream>>>(ctab, stab);
  cast_x_k<<<dim3(8192), dim3(256), 0, stream>>>(x, xb);
  transpose_w_k<<<dim3(64, 64, 4), dim3(256), 0, stream>>>(wq, wk, wv, wo, wT);
  gemm256_k<<<dim3(384), dim3(512), 131072, stream>>>(xb, wT, qkvb);
  norm_rope_k<<<dim3(16384, 2), dim3(256), 0, stream>>>(qkvb, qkn, gq, bq, gk, bk, ctab, stab);
  attn_k<<<dim3(16, 32), dim3(256), 81920, stream>>>(qkn, qkn + 8388608,
                                                     qkvb + 2 * (size_t)8388608, ob);
  gemm_bt_k<<<dim3(32, 16), dim3(256), 0, stream>>>(ob, wT + 3 * (size_t)4194304,
                                                    (float*)d_out, 2048);
}

// Round 10
// 285.656 us; speedup vs baseline: 1.4589x; 1.4589x over previous
//
#include <hip/hip_runtime.h>

// ---------------------------------------------------------------------------
// Fused MHA: B=2, T=2048, M=2048, H=16, D=128, causal, qk-centered-RMS-norm,
// half-split rotary, QK_SCALE = 1/D.
// Pipeline: cast/transposes -> QKV GEMM (256^2 8-wave, R4 minimal-sync loop;
// V tile-transposed) -> norm+rope (log2e/128 folded into Q) -> flash attn
// (QBLK=64, exp2 softmax, diag-only mask, defer-max, packed P) -> out GEMM.
// ---------------------------------------------------------------------------

#define NB 2
#define NT 2048
#define NM 2048
#define NH 16
#define ND 128

typedef __attribute__((ext_vector_type(4))) float f32x4;
typedef __attribute__((ext_vector_type(8))) short bf16x8;
typedef __attribute__((ext_vector_type(4))) short bf16x4;

#define AS1 __attribute__((address_space(1)))
#define AS3 __attribute__((address_space(3)))

__device__ __forceinline__ unsigned short f2bf(float f){
  unsigned int u = __float_as_uint(f);
  u = (u + 0x7fffu + ((u >> 16) & 1u)) >> 16;   // RNE
  return (unsigned short)u;
}
__device__ __forceinline__ float bf2f(short s){
  return __uint_as_float(((unsigned int)(unsigned short)s) << 16);
}
__device__ __forceinline__ float wredsum(float v){
  #pragma unroll
  for (int m = 1; m < 64; m <<= 1) v += __shfl_xor(v, m);
  return v;
}
__device__ __forceinline__ void gload_lds16(const void* g, void* l){
  __builtin_amdgcn_global_load_lds((const AS1 void*)g, (AS3 void*)l, 16, 0, 0);
}

// ---------------- rope cos/sin table: [T][64] each --------------------------
__global__ __launch_bounds__(64) void rope_table_k(float* ctab, float* stab){
  int t = blockIdx.x, i = threadIdx.x;
  float freq = __expf(-(float)i * (9.210340371976184f / 64.0f)); // ln(10000)
  float ang = (float)t * freq;
  ctab[t * 64 + i] = cosf(ang);
  stab[t * 64 + i] = sinf(ang);
}

// ---------------- cast x fp32 -> bf16 --------------------------------------
__global__ __launch_bounds__(256) void cast_x_k(const float* __restrict__ x,
                                                short* __restrict__ xb){
  size_t gid = (size_t)blockIdx.x * 256 + threadIdx.x;
  float4 v = *(const float4*)(x + gid * 4);
  bf16x4 o;
  o[0] = (short)f2bf(v.x); o[1] = (short)f2bf(v.y);
  o[2] = (short)f2bf(v.z); o[3] = (short)f2bf(v.w);
  *(bf16x4*)(xb + gid * 4) = o;
}

// ------------- transpose weights fp32 [K][N] -> bf16 [N][K] ----------------
__global__ __launch_bounds__(256) void transpose_w_k(const float* __restrict__ wq,
                                                     const float* __restrict__ wk,
                                                     const float* __restrict__ wv,
                                                     const float* __restrict__ wo,
                                                     short* __restrict__ wT){
  __shared__ float tl[32][33];
  int z = blockIdx.z;
  const float* src = (z == 0) ? wq : (z == 1) ? wk : (z == 2) ? wv : wo;
  short* dst = wT + (size_t)z * 2048 * 2048;
  int n0 = blockIdx.x * 32, k0 = blockIdx.y * 32;
  int cx = threadIdx.x & 31, ry = threadIdx.x >> 5; // 0..7
  #pragma unroll
  for (int p = 0; p < 4; ++p)
    tl[ry + 8 * p][cx] = src[(size_t)(k0 + ry + 8 * p) * 2048 + n0 + cx];
  __syncthreads();
  #pragma unroll
  for (int p = 0; p < 4; ++p)
    dst[(size_t)(n0 + ry + 8 * p) * 2048 + k0 + cx] =
        (short)f2bf(tl[cx][ry + 8 * p]);
}

// ---------------------------------------------------------------------------
// QKV GEMM: 256x256 tile, BK=64, 8 waves, 512 threads, 128 KiB dynamic LDS.
// R4 minimal-sync K-loop. tsel block-uniform. V tiled-transposed.
// ---------------------------------------------------------------------------
#define NKT 32   // 2048 / 64
__global__ __launch_bounds__(512, 2) void gemm256_k(const short* __restrict__ A,
                                                    const short* __restrict__ Bt,
                                                    short* __restrict__ Cq){
  extern __shared__ char lds[];
  const int tid = threadIdx.x;
  const int wid = tid >> 6, lane = tid & 63;
  const int lrow = lane & 15, g8 = lane >> 4;
  const int wm = wid >> 2, wn = wid & 3;
  const int Kdim = 2048;

  int bid = blockIdx.x;
  int s = (bid & 7) * 48 + (bid >> 3);
  const int bx = s & 15;
  const int by = s >> 4;
  const int m0 = bx * 256, n0 = by * 256;

  const int r8 = lane >> 3;
  const int gcol = ((lane & 7) ^ r8) * 8;
  const short* Ab = A  + (size_t)(m0 + wid * 8 + r8) * Kdim + gcol;
  const short* Bb = Bt + (size_t)(n0 + wid * 8 + r8) * Kdim + gcol;

  f32x4 acc[8][4] = {};

  auto STAGE = [&](int c, int kt){
    #pragma unroll
    for (int h = 0; h < 2; ++h)
      #pragma unroll
      for (int l = 0; l < 2; ++l){
        size_t roff = (size_t)(h * 128 + l * 64) * Kdim + kt * 64;
        char* la = lds + c * 32768 + h * 16384 + l * 8192 + wid * 1024;
        gload_lds16(Ab + roff, la);
        gload_lds16(Bb + roff, la + 65536);
      }
  };
  auto ldA = [&](int c, int mi, int kk) -> bf16x8 {
    int row = mi * 16 + lrow;
    int col = (kk * 64 + g8 * 16) ^ ((lrow & 7) << 4);
    return *(const bf16x8*)(lds + c * 32768 + wm * 16384 + row * 128 + col);
  };
  auto ldB = [&](int c, int ni, int kk) -> bf16x8 {
    int row = (wn & 1) * 64 + ni * 16 + lrow;
    int col = (kk * 64 + g8 * 16) ^ ((lrow & 7) << 4);
    return *(const bf16x8*)(lds + 65536 + c * 32768 + (wn >> 1) * 16384 + row * 128 + col);
  };

  STAGE(0, 0);

  for (int kt = 0; kt < NKT; ++kt){
    const int c = kt & 1;
    asm volatile("s_waitcnt vmcnt(0)" ::: "memory");
    __builtin_amdgcn_s_barrier();
    if (kt + 1 < NKT) STAGE(c ^ 1, kt + 1);

    #pragma unroll
    for (int kk = 0; kk < 2; ++kk){
      bf16x8 bfr[4];
      #pragma unroll
      for (int ni = 0; ni < 4; ++ni) bfr[ni] = ldB(c, ni, kk);
      #pragma unroll
      for (int mh = 0; mh < 2; ++mh){
        bf16x8 afr[4];
        #pragma unroll
        for (int mi = 0; mi < 4; ++mi) afr[mi] = ldA(c, mh * 4 + mi, kk);
        #pragma unroll
        for (int mi = 0; mi < 4; ++mi)
          #pragma unroll
          for (int ni = 0; ni < 4; ++ni)
            acc[mh * 4 + mi][ni] = __builtin_amdgcn_mfma_f32_16x16x32_bf16(
                afr[mi], bfr[ni], acc[mh * 4 + mi][ni], 0, 0, 0);
      }
    }
  }

  const int tsel = by >> 3;           // 0=q, 1=k, 2=v (block-uniform)
  short* dst = Cq + (size_t)tsel * (NB * NH * NT * ND);
  if (tsel < 2){
    #pragma unroll
    for (int mi = 0; mi < 8; ++mi){
      int rowb = m0 + wm * 128 + mi * 16 + g8 * 4;
      #pragma unroll
      for (int ni = 0; ni < 4; ++ni){
        int col = n0 + wn * 64 + ni * 16 + lrow;
        int hd = col & 2047;
        int hh = hd >> 7, d = hd & 127;
        f32x4 a = acc[mi][ni];
        #pragma unroll
        for (int r = 0; r < 4; ++r){
          int bt = rowb + r;
          int b = bt >> 11, t = bt & 2047;
          dst[(((size_t)(b * NH + hh)) * NT + t) * ND + d] = (short)f2bf(a[r]);
        }
      }
    }
  } else {
    #pragma unroll
    for (int mi = 0; mi < 8; ++mi){
      int rowb = m0 + wm * 128 + mi * 16 + g8 * 4;
      int b = rowb >> 11, t0 = rowb & 2047;
      int jb = t0 >> 6, toff = t0 & 63;
      #pragma unroll
      for (int ni = 0; ni < 4; ++ni){
        int col = n0 + wn * 64 + ni * 16 + lrow;
        int hd = col & 2047;
        int hh = hd >> 7, d = hd & 127;
        f32x4 a = acc[mi][ni];
        bf16x4 w4;
        #pragma unroll
        for (int r = 0; r < 4; ++r) w4[r] = (short)f2bf(a[r]);
        *(bf16x4*)&dst[(((size_t)(b * NH + hh) * 32 + jb) * ND + d) * 64 + toff] = w4;
      }
    }
  }
}

// ---------------- out-proj GEMM (128^2, double-buffered, 1-barrier) --------
__global__ __launch_bounds__(256) void gemm_bt_k(const short* __restrict__ A,
                                                 const short* __restrict__ Bt,
                                                 float* __restrict__ Cout,
                                                 int Kdim){
  __shared__ short As[2][128 * 32];
  __shared__ short Bs[2][128 * 32];
  const int tid = threadIdx.x;
  const int wid = tid >> 6, lane = tid & 63;
  const int lrow = lane & 15, g8 = lane >> 4;
  const int wm = wid >> 1, wn = wid & 1;
  const int m0 = blockIdx.x * 128, n0 = blockIdx.y * 128;
  f32x4 acc[4][4] = {};
  const int srow = lane >> 2;
  const int skcol = (lane & 3) * 8;

  auto STAGE = [&](int c, int kt){
    #pragma unroll
    for (int i = 0; i < 2; ++i){
      int inst = wid * 2 + i;
      int r = inst * 16 + srow;
      const short* sa = A  + (size_t)(m0 + r) * Kdim + kt + skcol;
      const short* sb = Bt + (size_t)(n0 + r) * Kdim + kt + skcol;
      gload_lds16(sa, (char*)As[c] + inst * 1024);
      gload_lds16(sb, (char*)Bs[c] + inst * 1024);
    }
  };

  STAGE(0, 0);
  const int nkt = Kdim >> 5;
  for (int it = 0; it < nkt; ++it){
    const int c = it & 1;
    asm volatile("s_waitcnt vmcnt(0)" ::: "memory");
    __builtin_amdgcn_s_barrier();
    if (it + 1 < nkt) STAGE(c ^ 1, (it + 1) << 5);

    bf16x8 af[4], bfv[4];
    #pragma unroll
    for (int mi = 0; mi < 4; ++mi)
      af[mi] = *(const bf16x8*)&As[c][(wm * 64 + mi * 16 + lrow) * 32 + g8 * 8];
    #pragma unroll
    for (int ni = 0; ni < 4; ++ni)
      bfv[ni] = *(const bf16x8*)&Bs[c][(wn * 64 + ni * 16 + lrow) * 32 + g8 * 8];
    #pragma unroll
    for (int mi = 0; mi < 4; ++mi)
      #pragma unroll
      for (int ni = 0; ni < 4; ++ni)
        acc[mi][ni] = __builtin_amdgcn_mfma_f32_16x16x32_bf16(
            af[mi], bfv[ni], acc[mi][ni], 0, 0, 0);
  }

  #pragma unroll
  for (int mi = 0; mi < 4; ++mi){
    int rowb = m0 + wm * 64 + mi * 16 + g8 * 4;
    #pragma unroll
    for (int ni = 0; ni < 4; ++ni){
      int col = n0 + wn * 64 + ni * 16 + lrow;
      f32x4 a = acc[mi][ni];
      #pragma unroll
      for (int r = 0; r < 4; ++r)
        Cout[(size_t)(rowb + r) * 2048 + col] = a[r];
    }
  }
}

// -------------- centered RMS norm + rotary (q and k) -----------------------
// Q outputs are scaled by log2(e)/128 so attention can use exp2 directly.
__global__ __launch_bounds__(256) void norm_rope_k(const short* __restrict__ qkv,
                                                   short* __restrict__ outp,
                                                   const float* __restrict__ gq,
                                                   const float* __restrict__ bq,
                                                   const float* __restrict__ gk,
                                                   const float* __restrict__ bk,
                                                   const float* __restrict__ ctab,
                                                   const float* __restrict__ stab){
  int which = blockIdx.y;
  const short* src = qkv + (size_t)which * (NB * NH * NT * ND);
  short* dst = outp + (size_t)which * (NB * NH * NT * ND);
  const float* g = which ? gk : gq;
  const float* bb = which ? bk : bq;
  const float qs = which ? 1.0f : 0.011271055007f;   // log2(e)/128
  int wid = threadIdx.x >> 6, lane = threadIdx.x & 63;
  size_t row = (size_t)blockIdx.x * 4 + wid;  // over B*H*T
  int h = (int)((row >> 11) & 15);
  int t = (int)(row & 2047);
  const short* rp = src + row * ND;
  float v0 = bf2f(rp[lane]), v1 = bf2f(rp[lane + 64]);
  float mean = wredsum(v0 + v1) * (1.0f / 128.0f);
  float c0 = v0 - mean, c1 = v1 - mean;
  float ms = wredsum(c0 * c0 + c1 * c1) * (1.0f / 128.0f);
  float rstd = rsqrtf(ms + 1e-6f);
  float n0 = c0 * rstd * (1.0f + g[h * ND + lane]) + bb[h * ND + lane];
  float n1 = c1 * rstd * (1.0f + g[h * ND + lane + 64]) + bb[h * ND + lane + 64];
  float co = ctab[t * 64 + lane], si = stab[t * 64 + lane];
  short* wp = dst + row * ND;
  wp[lane]      = (short)f2bf((n0 * co - n1 * si) * qs);
  wp[lane + 64] = (short)f2bf((n0 * si + n1 * co) * qs);
}

// ---------------- flash attention, causal, QBLK=64 -------------------------
// R8 structure + VALU cuts: exp2 softmax (scale pre-folded into Q), mask only
// on the diagonal tile (block-uniform), defer-max (THR=8, exact), packed
// cvt_pk P-writes (1 ds_write_b64 per 4 elems). Flat grid id=qx*32+bh so
// same-bh blocks share an XCD (L2 locality). One barrier per tile.
// LDS: K[2][16KB] | V^T[2][16KB] | Ps[4][2KB] = 72 KiB dynamic.
__global__ __launch_bounds__(256) void attn_k(const short* __restrict__ qn,
                                              const short* __restrict__ kn,
                                              const short* __restrict__ vt,
                                              short* __restrict__ ob){
  extern __shared__ char lds[];
  const int tid = threadIdx.x;
  const int wid = tid >> 6, lane = tid & 63;
  const int lrow = lane & 15, g8 = lane >> 4;
  const int id = blockIdx.x;
  const int qx = id >> 5;             // 0..15
  const int bh = id & 31;             // same-bh ids are congruent mod 8
  const int b = bh >> 4, h = bh & 15;
  const size_t base = (size_t)bh * NT * ND;
  char* Pw = lds + 65536 + wid * 2048;

  auto STAGE = [&](int cb, int jb){
    #pragma unroll
    for (int i = 0; i < 4; ++i){
      int r0 = wid * 16 + i * 4;
      int r = r0 + (lane >> 4);
      int g = lane & 15;
      gload_lds16(kn + base + (size_t)(jb * 64 + r) * ND + ((g ^ (r & 7)) << 3),
                  lds + cb * 16384 + r0 * 256);
    }
    #pragma unroll
    for (int i = 0; i < 4; ++i){
      int d0 = wid * 32 + i * 8;
      int d = d0 + (lane >> 3);
      int g = lane & 7;
      gload_lds16(vt + base + (size_t)jb * 8192 + d * 64 + ((g ^ (d & 7)) << 3),
                  lds + 32768 + cb * 16384 + d0 * 128);
    }
  };

  for (int pass = 0; pass < 2; ++pass){
    const int qt = pass ? (31 - qx) : qx;
    const int t0 = qt * 64;
    const int tq = t0 + wid * 16 + lrow;
    bf16x8 qf[4];
    #pragma unroll
    for (int dc = 0; dc < 4; ++dc)
      qf[dc] = *(const bf16x8*)(qn + base + (size_t)tq * ND + dc * 32 + g8 * 8);
    f32x4 O[8] = {};
    float m = -3e38f, lsum = 0.0f;

    __syncthreads();             // protect LDS buffers from previous pass
    STAGE(0, 0);

    for (int jb = 0; jb <= qt; ++jb){
      const int cb = jb & 1;
      asm volatile("s_waitcnt vmcnt(0)" ::: "memory");
      __builtin_amdgcn_s_barrier();          // tile jb resident
      if (jb < qt) STAGE(cb ^ 1, jb + 1);    // prefetch overlaps compute
      const char* Kb = lds + cb * 16384;
      const char* Vb = lds + 32768 + cb * 16384;

      if (jb * 64 <= t0 + wid * 16 + 15){
        // ---- S^T = K * Q^T (already scaled by log2e/128) ----
        f32x4 st[4] = {};
        __builtin_amdgcn_s_setprio(1);
        #pragma unroll
        for (int dc = 0; dc < 4; ++dc)
          #pragma unroll
          for (int js = 0; js < 4; ++js){
            int jl = js * 16 + lrow;
            bf16x8 kf = *(const bf16x8*)(Kb + jl * 256 +
                          (((dc * 4 + g8) ^ (jl & 7)) << 4));
            st[js] = __builtin_amdgcn_mfma_f32_16x16x32_bf16(kf, qf[dc], st[js], 0, 0, 0);
          }
        __builtin_amdgcn_s_setprio(0);
        // ---- causal mask only on the diagonal tile (block-uniform) ----
        if (jb == qt){
          #pragma unroll
          for (int js = 0; js < 4; ++js)
            #pragma unroll
            for (int r = 0; r < 4; ++r){
              int j = jb * 64 + js * 16 + g8 * 4 + r;
              if (j > tq) st[js][r] = -3e38f;
            }
        }
        // ---- row max (tree) ----
        f32x4 m4 = st[0];
        #pragma unroll
        for (int js = 1; js < 4; ++js)
          #pragma unroll
          for (int r = 0; r < 4; ++r) m4[r] = fmaxf(m4[r], st[js][r]);
        float mx = fmaxf(fmaxf(m4[0], m4[1]), fmaxf(m4[2], m4[3]));
        mx = fmaxf(mx, __shfl_xor(mx, 16));
        mx = fmaxf(mx, __shfl_xor(mx, 32));
        // ---- defer-max: rescale only when max grew by >8 (P <= 2^8) ----
        if (!__all(mx <= m + 8.0f)){
          float mnew = fmaxf(m, mx);
          float fac = exp2f(m - mnew);
          m = mnew;
          lsum *= fac;
          #pragma unroll
          for (int dcb = 0; dcb < 8; ++dcb) O[dcb] *= fac;
        }
        // ---- P = exp2(S - m), packed bf16 pair writes ----
        float ps = 0.0f;
        #pragma unroll
        for (int js = 0; js < 4; ++js){
          float p0 = exp2f(st[js][0] - m);
          float p1 = exp2f(st[js][1] - m);
          float p2 = exp2f(st[js][2] - m);
          float p3 = exp2f(st[js][3] - m);
          ps += (p0 + p1) + (p2 + p3);
          unsigned int lo, hi;
          asm("v_cvt_pk_bf16_f32 %0, %1, %2" : "=v"(lo) : "v"(p0), "v"(p1));
          asm("v_cvt_pk_bf16_f32 %0, %1, %2" : "=v"(hi) : "v"(p2), "v"(p3));
          uint2 w; w.x = lo; w.y = hi;
          *(uint2*)(Pw + lrow * 128 + ((js * 32 + g8 * 8) ^ ((lrow & 7) << 4))) = w;
        }
        ps += __shfl_xor(ps, 16);
        ps += __shfl_xor(ps, 32);
        lsum += ps;
        asm volatile("s_waitcnt lgkmcnt(0)" ::: "memory");
        // ---- O^T += V^T * P^T ----
        __builtin_amdgcn_s_setprio(1);
        #pragma unroll
        for (int j32 = 0; j32 < 2; ++j32){
          bf16x8 pf = *(const bf16x8*)(Pw + lrow * 128 +
                        ((j32 * 64 + g8 * 16) ^ ((lrow & 7) << 4)));
          #pragma unroll
          for (int dcb = 0; dcb < 8; ++dcb){
            int d = dcb * 16 + lrow;
            bf16x8 vf = *(const bf16x8*)(Vb + d * 128 +
                          (((j32 * 4 + g8) ^ (d & 7)) << 4));
            O[dcb] = __builtin_amdgcn_mfma_f32_16x16x32_bf16(vf, pf, O[dcb], 0, 0, 0);
          }
        }
        __builtin_amdgcn_s_setprio(0);
      }
    }
    // ---- write O row tq as bf16 into [bt][h*128+d] ----
    float inv = 1.0f / lsum;
    #pragma unroll
    for (int dcb = 0; dcb < 8; ++dcb){
      bf16x4 w4;
      #pragma unroll
      for (int r = 0; r < 4; ++r) w4[r] = (short)f2bf(O[dcb][r] * inv);
      *(bf16x4*)(ob + ((size_t)(b * NT + tq)) * (NH * ND) + h * ND + dcb * 16 + g8 * 4) = w4;
    }
  }
}

// ---------------------------------------------------------------------------
extern "C" void kernel_launch(void* const* d_in, const int* in_sizes, int n_in,
                              void* d_out, int out_size, void* d_ws, size_t ws_size,
                              hipStream_t stream){
  const float* x  = (const float*)d_in[0];
  const float* wq = (const float*)d_in[1];
  const float* wk = (const float*)d_in[2];
  const float* wv = (const float*)d_in[3];
  const float* wo = (const float*)d_in[4];
  const float* gq = (const float*)d_in[5];
  const float* bq = (const float*)d_in[6];
  const float* gk = (const float*)d_in[7];
  const float* bk = (const float*)d_in[8];

  char* ws = (char*)d_ws;
  short* xb   = (short*)(ws);                      // 16,777,216 B
  short* wT   = (short*)(ws + 16777216);           // 33,554,432 B (q,k,v,o ^T)
  short* qkvb = (short*)(ws + 50331648);           // 50,331,648 B (q|k|v^T bf16)
  short* qkn  = (short*)(ws + 100663296);          // 33,554,432 B (qn|kn)
  short* ob   = (short*)(ws + 134217728);          // 16,777,216 B
  float* ctab = (float*)(ws + 150994944);          // 524,288 B
  float* stab = (float*)(ws + 151519232);          // 524,288 B

  (void)hipFuncSetAttribute((const void*)gemm256_k,
                            hipFuncAttributeMaxDynamicSharedMemorySize, 131072);
  (void)hipFuncSetAttribute((const void*)attn_k,
                            hipFuncAttributeMaxDynamicSharedMemorySize, 73728);

  rope_table_k<<<dim3(2048), dim3(64), 0, stream>>>(ctab, stab);
  cast_x_k<<<dim3(8192), dim3(256), 0, stream>>>(x, xb);
  transpose_w_k<<<dim3(64, 64, 4), dim3(256), 0, stream>>>(wq, wk, wv, wo, wT);
  gemm256_k<<<dim3(384), dim3(512), 131072, stream>>>(xb, wT, qkvb);
  norm_rope_k<<<dim3(16384, 2), dim3(256), 0, stream>>>(qkvb, qkn, gq, bq, gk, bk, ctab, stab);
  attn_k<<<dim3(512), dim3(256), 73728, stream>>>(qkn, qkn + 8388608,
                                                  qkvb + 2 * (size_t)8388608, ob);
  gemm_bt_k<<<dim3(32, 16), dim3(256), 0, stream>>>(ob, wT + 3 * (size_t)4194304,
                                                    (float*)d_out, 2048);
}

// Round 11
// 277.223 us; speedup vs baseline: 1.5032x; 1.0304x over previous
//
#include <hip/hip_runtime.h>

// ---------------------------------------------------------------------------
// Fused MHA: B=2, T=2048, M=2048, H=16, D=128, causal, qk-centered-RMS-norm,
// half-split rotary, QK_SCALE = 1/D.
// Pipeline: prep (cast|transpose|rope fused) -> QKV GEMM (256^2 8-wave, R4
// minimal-sync; V tile-transposed) -> norm+rope (log2e/128 in Q) -> flash
// attn v3 (QBLK=128, 8 waves, triple-buffer, counted vmcnt) -> out GEMM.
// ---------------------------------------------------------------------------

#define NB 2
#define NT 2048
#define NM 2048
#define NH 16
#define ND 128

typedef __attribute__((ext_vector_type(4))) float f32x4;
typedef __attribute__((ext_vector_type(8))) short bf16x8;
typedef __attribute__((ext_vector_type(4))) short bf16x4;

#define AS1 __attribute__((address_space(1)))
#define AS3 __attribute__((address_space(3)))

__device__ __forceinline__ unsigned short f2bf(float f){
  unsigned int u = __float_as_uint(f);
  u = (u + 0x7fffu + ((u >> 16) & 1u)) >> 16;   // RNE
  return (unsigned short)u;
}
__device__ __forceinline__ float bf2f(short s){
  return __uint_as_float(((unsigned int)(unsigned short)s) << 16);
}
__device__ __forceinline__ float wredsum(float v){
  #pragma unroll
  for (int m = 1; m < 64; m <<= 1) v += __shfl_xor(v, m);
  return v;
}
__device__ __forceinline__ void gload_lds16(const void* g, void* l){
  __builtin_amdgcn_global_load_lds((const AS1 void*)g, (AS3 void*)l, 16, 0, 0);
}

// ------------- fused prep: cast x | transpose weights | rope table ---------
// grid.x: [0,8192) cast, [8192,24576) transpose (64x64x4), [24576,25088) rope
__global__ __launch_bounds__(256) void prep_k(const float* __restrict__ x,
                                              const float* __restrict__ wq,
                                              const float* __restrict__ wk,
                                              const float* __restrict__ wv,
                                              const float* __restrict__ wo,
                                              short* __restrict__ xb,
                                              short* __restrict__ wT,
                                              float* __restrict__ ctab,
                                              float* __restrict__ stab){
  __shared__ float tl[32][33];
  const int bid = blockIdx.x, tid = threadIdx.x;
  if (bid < 8192){
    size_t gid = (size_t)bid * 256 + tid;
    float4 v = *(const float4*)(x + gid * 4);
    bf16x4 o;
    o[0] = (short)f2bf(v.x); o[1] = (short)f2bf(v.y);
    o[2] = (short)f2bf(v.z); o[3] = (short)f2bf(v.w);
    *(bf16x4*)(xb + gid * 4) = o;
  } else if (bid < 24576){
    int tb = bid - 8192;
    int z = tb >> 12, rem = tb & 4095;
    int n0 = (rem & 63) * 32, k0 = (rem >> 6) * 32;
    const float* src = (z == 0) ? wq : (z == 1) ? wk : (z == 2) ? wv : wo;
    short* dst = wT + (size_t)z * 2048 * 2048;
    int cx = tid & 31, ry = tid >> 5; // 0..7
    #pragma unroll
    for (int p = 0; p < 4; ++p)
      tl[ry + 8 * p][cx] = src[(size_t)(k0 + ry + 8 * p) * 2048 + n0 + cx];
    __syncthreads();
    #pragma unroll
    for (int p = 0; p < 4; ++p)
      dst[(size_t)(n0 + ry + 8 * p) * 2048 + k0 + cx] =
          (short)f2bf(tl[cx][ry + 8 * p]);
  } else {
    int t = (bid - 24576) * 4 + (tid >> 6);
    int i = tid & 63;
    float freq = __expf(-(float)i * (9.210340371976184f / 64.0f)); // ln(10000)
    float ang = (float)t * freq;
    ctab[t * 64 + i] = cosf(ang);
    stab[t * 64 + i] = sinf(ang);
  }
}

// ---------------------------------------------------------------------------
// QKV GEMM: 256x256 tile, BK=64, 8 waves, 512 threads, 128 KiB dynamic LDS.
// R4 minimal-sync K-loop. tsel block-uniform. V tiled-transposed.
// ---------------------------------------------------------------------------
#define NKT 32   // 2048 / 64
__global__ __launch_bounds__(512, 2) void gemm256_k(const short* __restrict__ A,
                                                    const short* __restrict__ Bt,
                                                    short* __restrict__ Cq){
  extern __shared__ char lds[];
  const int tid = threadIdx.x;
  const int wid = tid >> 6, lane = tid & 63;
  const int lrow = lane & 15, g8 = lane >> 4;
  const int wm = wid >> 2, wn = wid & 3;
  const int Kdim = 2048;

  int bid = blockIdx.x;
  int s = (bid & 7) * 48 + (bid >> 3);
  const int bx = s & 15;
  const int by = s >> 4;
  const int m0 = bx * 256, n0 = by * 256;

  const int r8 = lane >> 3;
  const int gcol = ((lane & 7) ^ r8) * 8;
  const short* Ab = A  + (size_t)(m0 + wid * 8 + r8) * Kdim + gcol;
  const short* Bb = Bt + (size_t)(n0 + wid * 8 + r8) * Kdim + gcol;

  f32x4 acc[8][4] = {};

  auto STAGE = [&](int c, int kt){
    #pragma unroll
    for (int h = 0; h < 2; ++h)
      #pragma unroll
      for (int l = 0; l < 2; ++l){
        size_t roff = (size_t)(h * 128 + l * 64) * Kdim + kt * 64;
        char* la = lds + c * 32768 + h * 16384 + l * 8192 + wid * 1024;
        gload_lds16(Ab + roff, la);
        gload_lds16(Bb + roff, la + 65536);
      }
  };
  auto ldA = [&](int c, int mi, int kk) -> bf16x8 {
    int row = mi * 16 + lrow;
    int col = (kk * 64 + g8 * 16) ^ ((lrow & 7) << 4);
    return *(const bf16x8*)(lds + c * 32768 + wm * 16384 + row * 128 + col);
  };
  auto ldB = [&](int c, int ni, int kk) -> bf16x8 {
    int row = (wn & 1) * 64 + ni * 16 + lrow;
    int col = (kk * 64 + g8 * 16) ^ ((lrow & 7) << 4);
    return *(const bf16x8*)(lds + 65536 + c * 32768 + (wn >> 1) * 16384 + row * 128 + col);
  };

  STAGE(0, 0);

  for (int kt = 0; kt < NKT; ++kt){
    const int c = kt & 1;
    asm volatile("s_waitcnt vmcnt(0)" ::: "memory");
    __builtin_amdgcn_s_barrier();
    if (kt + 1 < NKT) STAGE(c ^ 1, kt + 1);

    #pragma unroll
    for (int kk = 0; kk < 2; ++kk){
      bf16x8 bfr[4];
      #pragma unroll
      for (int ni = 0; ni < 4; ++ni) bfr[ni] = ldB(c, ni, kk);
      #pragma unroll
      for (int mh = 0; mh < 2; ++mh){
        bf16x8 afr[4];
        #pragma unroll
        for (int mi = 0; mi < 4; ++mi) afr[mi] = ldA(c, mh * 4 + mi, kk);
        #pragma unroll
        for (int mi = 0; mi < 4; ++mi)
          #pragma unroll
          for (int ni = 0; ni < 4; ++ni)
            acc[mh * 4 + mi][ni] = __builtin_amdgcn_mfma_f32_16x16x32_bf16(
                afr[mi], bfr[ni], acc[mh * 4 + mi][ni], 0, 0, 0);
      }
    }
  }

  const int tsel = by >> 3;           // 0=q, 1=k, 2=v (block-uniform)
  short* dst = Cq + (size_t)tsel * (NB * NH * NT * ND);
  if (tsel < 2){
    #pragma unroll
    for (int mi = 0; mi < 8; ++mi){
      int rowb = m0 + wm * 128 + mi * 16 + g8 * 4;
      #pragma unroll
      for (int ni = 0; ni < 4; ++ni){
        int col = n0 + wn * 64 + ni * 16 + lrow;
        int hd = col & 2047;
        int hh = hd >> 7, d = hd & 127;
        f32x4 a = acc[mi][ni];
        #pragma unroll
        for (int r = 0; r < 4; ++r){
          int bt = rowb + r;
          int b = bt >> 11, t = bt & 2047;
          dst[(((size_t)(b * NH + hh)) * NT + t) * ND + d] = (short)f2bf(a[r]);
        }
      }
    }
  } else {
    #pragma unroll
    for (int mi = 0; mi < 8; ++mi){
      int rowb = m0 + wm * 128 + mi * 16 + g8 * 4;
      int b = rowb >> 11, t0 = rowb & 2047;
      int jb = t0 >> 6, toff = t0 & 63;
      #pragma unroll
      for (int ni = 0; ni < 4; ++ni){
        int col = n0 + wn * 64 + ni * 16 + lrow;
        int hd = col & 2047;
        int hh = hd >> 7, d = hd & 127;
        f32x4 a = acc[mi][ni];
        bf16x4 w4;
        #pragma unroll
        for (int r = 0; r < 4; ++r) w4[r] = (short)f2bf(a[r]);
        *(bf16x4*)&dst[(((size_t)(b * NH + hh) * 32 + jb) * ND + d) * 64 + toff] = w4;
      }
    }
  }
}

// ---------------- out-proj GEMM (128^2, double-buffered, 1-barrier) --------
__global__ __launch_bounds__(256) void gemm_bt_k(const short* __restrict__ A,
                                                 const short* __restrict__ Bt,
                                                 float* __restrict__ Cout,
                                                 int Kdim){
  __shared__ short As[2][128 * 32];
  __shared__ short Bs[2][128 * 32];
  const int tid = threadIdx.x;
  const int wid = tid >> 6, lane = tid & 63;
  const int lrow = lane & 15, g8 = lane >> 4;
  const int wm = wid >> 1, wn = wid & 1;
  const int m0 = blockIdx.x * 128, n0 = blockIdx.y * 128;
  f32x4 acc[4][4] = {};
  const int srow = lane >> 2;
  const int skcol = (lane & 3) * 8;

  auto STAGE = [&](int c, int kt){
    #pragma unroll
    for (int i = 0; i < 2; ++i){
      int inst = wid * 2 + i;
      int r = inst * 16 + srow;
      const short* sa = A  + (size_t)(m0 + r) * Kdim + kt + skcol;
      const short* sb = Bt + (size_t)(n0 + r) * Kdim + kt + skcol;
      gload_lds16(sa, (char*)As[c] + inst * 1024);
      gload_lds16(sb, (char*)Bs[c] + inst * 1024);
    }
  };

  STAGE(0, 0);
  const int nkt = Kdim >> 5;
  for (int it = 0; it < nkt; ++it){
    const int c = it & 1;
    asm volatile("s_waitcnt vmcnt(0)" ::: "memory");
    __builtin_amdgcn_s_barrier();
    if (it + 1 < nkt) STAGE(c ^ 1, (it + 1) << 5);

    bf16x8 af[4], bfv[4];
    #pragma unroll
    for (int mi = 0; mi < 4; ++mi)
      af[mi] = *(const bf16x8*)&As[c][(wm * 64 + mi * 16 + lrow) * 32 + g8 * 8];
    #pragma unroll
    for (int ni = 0; ni < 4; ++ni)
      bfv[ni] = *(const bf16x8*)&Bs[c][(wn * 64 + ni * 16 + lrow) * 32 + g8 * 8];
    #pragma unroll
    for (int mi = 0; mi < 4; ++mi)
      #pragma unroll
      for (int ni = 0; ni < 4; ++ni)
        acc[mi][ni] = __builtin_amdgcn_mfma_f32_16x16x32_bf16(
            af[mi], bfv[ni], acc[mi][ni], 0, 0, 0);
  }

  #pragma unroll
  for (int mi = 0; mi < 4; ++mi){
    int rowb = m0 + wm * 64 + mi * 16 + g8 * 4;
    #pragma unroll
    for (int ni = 0; ni < 4; ++ni){
      int col = n0 + wn * 64 + ni * 16 + lrow;
      f32x4 a = acc[mi][ni];
      #pragma unroll
      for (int r = 0; r < 4; ++r)
        Cout[(size_t)(rowb + r) * 2048 + col] = a[r];
    }
  }
}

// -------------- centered RMS norm + rotary (q and k) -----------------------
// Q outputs are scaled by log2(e)/128 so attention can use exp2 directly.
__global__ __launch_bounds__(256) void norm_rope_k(const short* __restrict__ qkv,
                                                   short* __restrict__ outp,
                                                   const float* __restrict__ gq,
                                                   const float* __restrict__ bq,
                                                   const float* __restrict__ gk,
                                                   const float* __restrict__ bk,
                                                   const float* __restrict__ ctab,
                                                   const float* __restrict__ stab){
  int which = blockIdx.y;
  const short* src = qkv + (size_t)which * (NB * NH * NT * ND);
  short* dst = outp + (size_t)which * (NB * NH * NT * ND);
  const float* g = which ? gk : gq;
  const float* bb = which ? bk : bq;
  const float qs = which ? 1.0f : 0.011271055007f;   // log2(e)/128
  int wid = threadIdx.x >> 6, lane = threadIdx.x & 63;
  size_t row = (size_t)blockIdx.x * 4 + wid;  // over B*H*T
  int h = (int)((row >> 11) & 15);
  int t = (int)(row & 2047);
  const short* rp = src + row * ND;
  float v0 = bf2f(rp[lane]), v1 = bf2f(rp[lane + 64]);
  float mean = wredsum(v0 + v1) * (1.0f / 128.0f);
  float c0 = v0 - mean, c1 = v1 - mean;
  float ms = wredsum(c0 * c0 + c1 * c1) * (1.0f / 128.0f);
  float rstd = rsqrtf(ms + 1e-6f);
  float n0 = c0 * rstd * (1.0f + g[h * ND + lane]) + bb[h * ND + lane];
  float n1 = c1 * rstd * (1.0f + g[h * ND + lane + 64]) + bb[h * ND + lane + 64];
  float co = ctab[t * 64 + lane], si = stab[t * 64 + lane];
  short* wp = dst + row * ND;
  wp[lane]      = (short)f2bf((n0 * co - n1 * si) * qs);
  wp[lane + 64] = (short)f2bf((n0 * si + n1 * co) * qs);
}

// ---------------- flash attention v3: QBLK=128, 8 waves, triple-buffer -----
// Grid 256 = 8 qs x 32 bh (1 block/CU, all resident, 34 tiles each via
// pass-pairing). Counted vmcnt pipeline: per tile {vmcnt(4); barrier;
// STAGE(jb+2); compute} -> DMA flight = 2 compute phases, never drained to 0
// mid-loop. LDS: K[3][16KB] | V^T[3][16KB] | P[8][2KB] = 112 KiB.
__global__ __launch_bounds__(512) void attn_k(const short* __restrict__ qn,
                                              const short* __restrict__ kn,
                                              const short* __restrict__ vt,
                                              short* __restrict__ ob){
  extern __shared__ char lds[];
  const int tid = threadIdx.x;
  const int wid = tid >> 6, lane = tid & 63;   // wid 0..7
  const int lrow = lane & 15, g8 = lane >> 4;
  const int id = blockIdx.x;
  const int qs = id >> 5;             // 0..7
  const int bh = id & 31;             // same-bh ids congruent mod 8 -> same XCD
  const int b = bh >> 4, h = bh & 15;
  const size_t base = (size_t)bh * NT * ND;
  char* Pw = lds + 98304 + wid * 2048;

  auto STAGE = [&](int jb){
    const int cb = jb % 3;
    #pragma unroll
    for (int i = 0; i < 2; ++i){
      int r0 = wid * 4 + i * 32;
      int r = r0 + (lane >> 4);
      int g = lane & 15;
      gload_lds16(kn + base + (size_t)(jb * 64 + r) * ND + ((g ^ (r & 7)) << 3),
                  lds + cb * 16384 + r0 * 256);
    }
    #pragma unroll
    for (int i = 0; i < 2; ++i){
      int d0 = wid * 8 + i * 64;
      int d = d0 + (lane >> 3);
      int g = lane & 7;
      gload_lds16(vt + base + (size_t)jb * 8192 + d * 64 + ((g ^ (d & 7)) << 3),
                  lds + 49152 + cb * 16384 + d0 * 128);
    }
  };

  for (int pass = 0; pass < 2; ++pass){
    const int qt = pass ? (15 - qs) : qs;      // supertile of 128 q-rows
    const int t0 = qt * 128;
    const int wrow0 = t0 + wid * 16;
    const int tq = wrow0 + lrow;
    bf16x8 qf[4];
    #pragma unroll
    for (int dc = 0; dc < 4; ++dc)
      qf[dc] = *(const bf16x8*)(qn + base + (size_t)tq * ND + dc * 32 + g8 * 8);
    f32x4 O[8] = {};
    float m = -3e38f, lsum = 0.0f;
    const int ntiles = 2 * qt + 2;

    __syncthreads();             // all reads of LDS from previous pass done
    STAGE(0);
    STAGE(1);

    for (int jb = 0; jb < ntiles; ++jb){
      if (jb + 1 < ntiles) asm volatile("s_waitcnt vmcnt(4)" ::: "memory");
      else                 asm volatile("s_waitcnt vmcnt(0)" ::: "memory");
      __builtin_amdgcn_s_barrier();          // tile jb resident
      if (jb + 2 < ntiles) STAGE(jb + 2);    // write buf (jb+2)%3: readers done
      const char* Kb = lds + (jb % 3) * 16384;
      const char* Vb = lds + 49152 + (jb % 3) * 16384;

      if (jb * 64 <= wrow0 + 15){
        // ---- S^T = K * Q^T (pre-scaled by log2e/128) ----
        f32x4 st[4] = {};
        __builtin_amdgcn_s_setprio(1);
        #pragma unroll
        for (int dc = 0; dc < 4; ++dc)
          #pragma unroll
          for (int js = 0; js < 4; ++js){
            int jl = js * 16 + lrow;
            bf16x8 kf = *(const bf16x8*)(Kb + jl * 256 +
                          (((dc * 4 + g8) ^ (jl & 7)) << 4));
            st[js] = __builtin_amdgcn_mfma_f32_16x16x32_bf16(kf, qf[dc], st[js], 0, 0, 0);
          }
        __builtin_amdgcn_s_setprio(0);
        // ---- causal mask only on tiles overlapping this wave's band ----
        if (jb * 64 + 63 > wrow0){
          #pragma unroll
          for (int js = 0; js < 4; ++js)
            #pragma unroll
            for (int r = 0; r < 4; ++r){
              int j = jb * 64 + js * 16 + g8 * 4 + r;
              if (j > tq) st[js][r] = -3e38f;
            }
        }
        // ---- row max (tree) ----
        f32x4 m4 = st[0];
        #pragma unroll
        for (int js = 1; js < 4; ++js)
          #pragma unroll
          for (int r = 0; r < 4; ++r) m4[r] = fmaxf(m4[r], st[js][r]);
        float mx = fmaxf(fmaxf(m4[0], m4[1]), fmaxf(m4[2], m4[3]));
        mx = fmaxf(mx, __shfl_xor(mx, 16));
        mx = fmaxf(mx, __shfl_xor(mx, 32));
        // ---- defer-max (THR=8) ----
        if (!__all(mx <= m + 8.0f)){
          float mnew = fmaxf(m, mx);
          float fac = exp2f(m - mnew);
          m = mnew;
          lsum *= fac;
          #pragma unroll
          for (int dcb = 0; dcb < 8; ++dcb) O[dcb] *= fac;
        }
        // ---- P = exp2(S - m), packed writes ----
        float ps = 0.0f;
        #pragma unroll
        for (int js = 0; js < 4; ++js){
          float p0 = exp2f(st[js][0] - m);
          float p1 = exp2f(st[js][1] - m);
          float p2 = exp2f(st[js][2] - m);
          float p3 = exp2f(st[js][3] - m);
          ps += (p0 + p1) + (p2 + p3);
          unsigned int lo, hi;
          asm("v_cvt_pk_bf16_f32 %0, %1, %2" : "=v"(lo) : "v"(p0), "v"(p1));
          asm("v_cvt_pk_bf16_f32 %0, %1, %2" : "=v"(hi) : "v"(p2), "v"(p3));
          uint2 w; w.x = lo; w.y = hi;
          *(uint2*)(Pw + lrow * 128 + ((js * 32 + g8 * 8) ^ ((lrow & 7) << 4))) = w;
        }
        ps += __shfl_xor(ps, 16);
        ps += __shfl_xor(ps, 32);
        lsum += ps;
        asm volatile("s_waitcnt lgkmcnt(0)" ::: "memory");
        // ---- O^T += V^T * P^T ----
        __builtin_amdgcn_s_setprio(1);
        #pragma unroll
        for (int j32 = 0; j32 < 2; ++j32){
          bf16x8 pf = *(const bf16x8*)(Pw + lrow * 128 +
                        ((j32 * 64 + g8 * 16) ^ ((lrow & 7) << 4)));
          #pragma unroll
          for (int dcb = 0; dcb < 8; ++dcb){
            int d = dcb * 16 + lrow;
            bf16x8 vf = *(const bf16x8*)(Vb + d * 128 +
                          (((j32 * 4 + g8) ^ (d & 7)) << 4));
            O[dcb] = __builtin_amdgcn_mfma_f32_16x16x32_bf16(vf, pf, O[dcb], 0, 0, 0);
          }
        }
        __builtin_amdgcn_s_setprio(0);
      }
    }
    // ---- write O rows as bf16 into [bt][h*128+d] ----
    float inv = 1.0f / lsum;
    #pragma unroll
    for (int dcb = 0; dcb < 8; ++dcb){
      bf16x4 w4;
      #pragma unroll
      for (int r = 0; r < 4; ++r) w4[r] = (short)f2bf(O[dcb][r] * inv);
      *(bf16x4*)(ob + ((size_t)(b * NT + tq)) * (NH * ND) + h * ND + dcb * 16 + g8 * 4) = w4;
    }
  }
}

// ---------------------------------------------------------------------------
extern "C" void kernel_launch(void* const* d_in, const int* in_sizes, int n_in,
                              void* d_out, int out_size, void* d_ws, size_t ws_size,
                              hipStream_t stream){
  const float* x  = (const float*)d_in[0];
  const float* wq = (const float*)d_in[1];
  const float* wk = (const float*)d_in[2];
  const float* wv = (const float*)d_in[3];
  const float* wo = (const float*)d_in[4];
  const float* gq = (const float*)d_in[5];
  const float* bq = (const float*)d_in[6];
  const float* gk = (const float*)d_in[7];
  const float* bk = (const float*)d_in[8];

  char* ws = (char*)d_ws;
  short* xb   = (short*)(ws);                      // 16,777,216 B
  short* wT   = (short*)(ws + 16777216);           // 33,554,432 B (q,k,v,o ^T)
  short* qkvb = (short*)(ws + 50331648);           // 50,331,648 B (q|k|v^T bf16)
  short* qkn  = (short*)(ws + 100663296);          // 33,554,432 B (qn|kn)
  short* ob   = (short*)(ws + 134217728);          // 16,777,216 B
  float* ctab = (float*)(ws + 150994944);          // 524,288 B
  float* stab = (float*)(ws + 151519232);          // 524,288 B

  (void)hipFuncSetAttribute((const void*)gemm256_k,
                            hipFuncAttributeMaxDynamicSharedMemorySize, 131072);
  (void)hipFuncSetAttribute((const void*)attn_k,
                            hipFuncAttributeMaxDynamicSharedMemorySize, 114688);

  prep_k<<<dim3(25088), dim3(256), 0, stream>>>(x, wq, wk, wv, wo, xb, wT, ctab, stab);
  gemm256_k<<<dim3(384), dim3(512), 131072, stream>>>(xb, wT, qkvb);
  norm_rope_k<<<dim3(16384, 2), dim3(256), 0, stream>>>(qkvb, qkn, gq, bq, gk, bk, ctab, stab);
  attn_k<<<dim3(256), dim3(512), 114688, stream>>>(qkn, qkn + 8388608,
                                                   qkvb + 2 * (size_t)8388608, ob);
  gemm_bt_k<<<dim3(32, 16), dim3(256), 0, stream>>>(ob, wT + 3 * (size_t)4194304,
                                                    (float*)d_out, 2048);
}

// Round 12
// 274.029 us; speedup vs baseline: 1.5207x; 1.0117x over previous
//
#include <hip/hip_runtime.h>

// ---------------------------------------------------------------------------
// Fused MHA: B=2, T=2048, M=2048, H=16, D=128, causal, qk-centered-RMS-norm,
// half-split rotary, QK_SCALE = 1/D.
// Pipeline: prep (cast|transpose|rope fused) -> QKV GEMM v2 (256x128 tile,
// BK=32, 8 waves, 2 blocks/CU) -> norm+rope (log2e/128 in Q) -> flash attn v3
// (QBLK=128, 8 waves, triple-buffer, counted vmcnt) -> out GEMM.
// ---------------------------------------------------------------------------

#define NB 2
#define NT 2048
#define NM 2048
#define NH 16
#define ND 128

typedef __attribute__((ext_vector_type(4))) float f32x4;
typedef __attribute__((ext_vector_type(8))) short bf16x8;
typedef __attribute__((ext_vector_type(4))) short bf16x4;

#define AS1 __attribute__((address_space(1)))
#define AS3 __attribute__((address_space(3)))

__device__ __forceinline__ unsigned short f2bf(float f){
  unsigned int u = __float_as_uint(f);
  u = (u + 0x7fffu + ((u >> 16) & 1u)) >> 16;   // RNE
  return (unsigned short)u;
}
__device__ __forceinline__ float bf2f(short s){
  return __uint_as_float(((unsigned int)(unsigned short)s) << 16);
}
__device__ __forceinline__ float wredsum(float v){
  #pragma unroll
  for (int m = 1; m < 64; m <<= 1) v += __shfl_xor(v, m);
  return v;
}
__device__ __forceinline__ void gload_lds16(const void* g, void* l){
  __builtin_amdgcn_global_load_lds((const AS1 void*)g, (AS3 void*)l, 16, 0, 0);
}

// ------------- fused prep: cast x | transpose weights | rope table ---------
__global__ __launch_bounds__(256) void prep_k(const float* __restrict__ x,
                                              const float* __restrict__ wq,
                                              const float* __restrict__ wk,
                                              const float* __restrict__ wv,
                                              const float* __restrict__ wo,
                                              short* __restrict__ xb,
                                              short* __restrict__ wT,
                                              float* __restrict__ ctab,
                                              float* __restrict__ stab){
  __shared__ float tl[32][33];
  const int bid = blockIdx.x, tid = threadIdx.x;
  if (bid < 8192){
    size_t gid = (size_t)bid * 256 + tid;
    float4 v = *(const float4*)(x + gid * 4);
    bf16x4 o;
    o[0] = (short)f2bf(v.x); o[1] = (short)f2bf(v.y);
    o[2] = (short)f2bf(v.z); o[3] = (short)f2bf(v.w);
    *(bf16x4*)(xb + gid * 4) = o;
  } else if (bid < 24576){
    int tb = bid - 8192;
    int z = tb >> 12, rem = tb & 4095;
    int n0 = (rem & 63) * 32, k0 = (rem >> 6) * 32;
    const float* src = (z == 0) ? wq : (z == 1) ? wk : (z == 2) ? wv : wo;
    short* dst = wT + (size_t)z * 2048 * 2048;
    int cx = tid & 31, ry = tid >> 5; // 0..7
    #pragma unroll
    for (int p = 0; p < 4; ++p)
      tl[ry + 8 * p][cx] = src[(size_t)(k0 + ry + 8 * p) * 2048 + n0 + cx];
    __syncthreads();
    #pragma unroll
    for (int p = 0; p < 4; ++p)
      dst[(size_t)(n0 + ry + 8 * p) * 2048 + k0 + cx] =
          (short)f2bf(tl[cx][ry + 8 * p]);
  } else {
    int t = (bid - 24576) * 4 + (tid >> 6);
    int i = tid & 63;
    float freq = __expf(-(float)i * (9.210340371976184f / 64.0f)); // ln(10000)
    float ang = (float)t * freq;
    ctab[t * 64 + i] = cosf(ang);
    stab[t * 64 + i] = sinf(ang);
  }
}

// ---------------------------------------------------------------------------
// QKV GEMM v2: C[4096 x 6144] = A[4096 x 2048] * B^T[6144 x 2048] (bf16)
// 256x128 tile, BK=32, 8 waves (4M x 2N, per-wave 64x64), 512 threads.
// LDS 48 KiB dbuf + launch_bounds(512,4) -> 2 blocks/CU co-resident: the
// partner block's waves absorb barrier/staging stalls (m114 mechanism).
// R4 minimal-sync loop. tsel block-uniform. V tiled-transposed.
// ---------------------------------------------------------------------------
#define NKT2 64   // 2048 / 32
__global__ __launch_bounds__(512, 4) void gemm256_k(const short* __restrict__ A,
                                                    const short* __restrict__ Bt,
                                                    short* __restrict__ Cq){
  extern __shared__ char lds[];   // A[2][16KB] @0 | B[2][8KB] @32768
  const int tid = threadIdx.x;
  const int wid = tid >> 6, lane = tid & 63;
  const int lrow = lane & 15, g8 = lane >> 4;
  const int wm = wid >> 1, wn = wid & 1;
  const int Kdim = 2048;

  // XCD-aware bijective swizzle over 768 blocks (768 % 8 == 0)
  int bid = blockIdx.x;
  int s = (bid & 7) * 96 + (bid >> 3);
  const int bx = s & 15;        // 16 m-tiles (256 rows)
  const int by = s >> 4;        // 48 n-tiles (128 cols)
  const int m0 = bx * 256, n0 = by * 128;

  // staging: 64-B rows (32 bf16), granule slot l&3 holds global granule
  // (l&3)^((l>>2)&3); read side XORs the same involution.
  const int ar = lane >> 2;                       // row within 16-row chunk
  const int ag = (lane & 3) ^ (ar & 3);           // inverse-swizzled granule
  const short* Ab = A  + (size_t)(m0 + wid * 32 + ar) * Kdim + ag * 8;
  const short* Bb = Bt + (size_t)(n0 + wid * 16 + ar) * Kdim + ag * 8;

  f32x4 acc[4][4] = {};

  auto STAGE = [&](int c, int kt){
    #pragma unroll
    for (int i = 0; i < 2; ++i)
      gload_lds16(Ab + (size_t)(i * 16) * Kdim + kt * 32,
                  lds + c * 16384 + wid * 2048 + i * 1024);
    gload_lds16(Bb + kt * 32, lds + 32768 + c * 8192 + wid * 1024);
  };
  auto ldA = [&](int c, int mi) -> bf16x8 {
    int row = wm * 64 + mi * 16 + lrow;
    return *(const bf16x8*)(lds + c * 16384 + row * 64 + ((g8 ^ (row & 3)) << 4));
  };
  auto ldB = [&](int c, int ni) -> bf16x8 {
    int row = wn * 64 + ni * 16 + lrow;
    return *(const bf16x8*)(lds + 32768 + c * 8192 + row * 64 + ((g8 ^ (row & 3)) << 4));
  };

  STAGE(0, 0);

  for (int kt = 0; kt < NKT2; ++kt){
    const int c = kt & 1;
    asm volatile("s_waitcnt vmcnt(0)" ::: "memory");
    __builtin_amdgcn_s_barrier();
    if (kt + 1 < NKT2) STAGE(c ^ 1, kt + 1);

    bf16x8 af[4], bfv[4];
    #pragma unroll
    for (int mi = 0; mi < 4; ++mi) af[mi] = ldA(c, mi);
    #pragma unroll
    for (int ni = 0; ni < 4; ++ni) bfv[ni] = ldB(c, ni);
    #pragma unroll
    for (int mi = 0; mi < 4; ++mi)
      #pragma unroll
      for (int ni = 0; ni < 4; ++ni)
        acc[mi][ni] = __builtin_amdgcn_mfma_f32_16x16x32_bf16(
            af[mi], bfv[ni], acc[mi][ni], 0, 0, 0);
  }

  const int tsel = by >> 4;           // 0=q, 1=k, 2=v (block-uniform)
  short* dst = Cq + (size_t)tsel * (NB * NH * NT * ND);
  if (tsel < 2){
    #pragma unroll
    for (int mi = 0; mi < 4; ++mi){
      int rowb = m0 + wm * 64 + mi * 16 + g8 * 4;
      #pragma unroll
      for (int ni = 0; ni < 4; ++ni){
        int col = n0 + wn * 64 + ni * 16 + lrow;
        int hd = col & 2047;
        int hh = hd >> 7, d = hd & 127;
        f32x4 a = acc[mi][ni];
        #pragma unroll
        for (int r = 0; r < 4; ++r){
          int bt = rowb + r;
          int b = bt >> 11, t = bt & 2047;
          dst[(((size_t)(b * NH + hh)) * NT + t) * ND + d] = (short)f2bf(a[r]);
        }
      }
    }
  } else {
    #pragma unroll
    for (int mi = 0; mi < 4; ++mi){
      int rowb = m0 + wm * 64 + mi * 16 + g8 * 4;
      int b = rowb >> 11, t0 = rowb & 2047;
      int jb = t0 >> 6, toff = t0 & 63;
      #pragma unroll
      for (int ni = 0; ni < 4; ++ni){
        int col = n0 + wn * 64 + ni * 16 + lrow;
        int hd = col & 2047;
        int hh = hd >> 7, d = hd & 127;
        f32x4 a = acc[mi][ni];
        bf16x4 w4;
        #pragma unroll
        for (int r = 0; r < 4; ++r) w4[r] = (short)f2bf(a[r]);
        *(bf16x4*)&dst[(((size_t)(b * NH + hh) * 32 + jb) * ND + d) * 64 + toff] = w4;
      }
    }
  }
}

// ---------------- out-proj GEMM (128^2, double-buffered, 1-barrier) --------
__global__ __launch_bounds__(256) void gemm_bt_k(const short* __restrict__ A,
                                                 const short* __restrict__ Bt,
                                                 float* __restrict__ Cout,
                                                 int Kdim){
  __shared__ short As[2][128 * 32];
  __shared__ short Bs[2][128 * 32];
  const int tid = threadIdx.x;
  const int wid = tid >> 6, lane = tid & 63;
  const int lrow = lane & 15, g8 = lane >> 4;
  const int wm = wid >> 1, wn = wid & 1;
  const int m0 = blockIdx.x * 128, n0 = blockIdx.y * 128;
  f32x4 acc[4][4] = {};
  const int srow = lane >> 2;
  const int skcol = (lane & 3) * 8;

  auto STAGE = [&](int c, int kt){
    #pragma unroll
    for (int i = 0; i < 2; ++i){
      int inst = wid * 2 + i;
      int r = inst * 16 + srow;
      const short* sa = A  + (size_t)(m0 + r) * Kdim + kt + skcol;
      const short* sb = Bt + (size_t)(n0 + r) * Kdim + kt + skcol;
      gload_lds16(sa, (char*)As[c] + inst * 1024);
      gload_lds16(sb, (char*)Bs[c] + inst * 1024);
    }
  };

  STAGE(0, 0);
  const int nkt = Kdim >> 5;
  for (int it = 0; it < nkt; ++it){
    const int c = it & 1;
    asm volatile("s_waitcnt vmcnt(0)" ::: "memory");
    __builtin_amdgcn_s_barrier();
    if (it + 1 < nkt) STAGE(c ^ 1, (it + 1) << 5);

    bf16x8 af[4], bfv[4];
    #pragma unroll
    for (int mi = 0; mi < 4; ++mi)
      af[mi] = *(const bf16x8*)&As[c][(wm * 64 + mi * 16 + lrow) * 32 + g8 * 8];
    #pragma unroll
    for (int ni = 0; ni < 4; ++ni)
      bfv[ni] = *(const bf16x8*)&Bs[c][(wn * 64 + ni * 16 + lrow) * 32 + g8 * 8];
    #pragma unroll
    for (int mi = 0; mi < 4; ++mi)
      #pragma unroll
      for (int ni = 0; ni < 4; ++ni)
        acc[mi][ni] = __builtin_amdgcn_mfma_f32_16x16x32_bf16(
            af[mi], bfv[ni], acc[mi][ni], 0, 0, 0);
  }

  #pragma unroll
  for (int mi = 0; mi < 4; ++mi){
    int rowb = m0 + wm * 64 + mi * 16 + g8 * 4;
    #pragma unroll
    for (int ni = 0; ni < 4; ++ni){
      int col = n0 + wn * 64 + ni * 16 + lrow;
      f32x4 a = acc[mi][ni];
      #pragma unroll
      for (int r = 0; r < 4; ++r)
        Cout[(size_t)(rowb + r) * 2048 + col] = a[r];
    }
  }
}

// -------------- centered RMS norm + rotary (q and k) -----------------------
// Q outputs are scaled by log2(e)/128 so attention can use exp2 directly.
__global__ __launch_bounds__(256) void norm_rope_k(const short* __restrict__ qkv,
                                                   short* __restrict__ outp,
                                                   const float* __restrict__ gq,
                                                   const float* __restrict__ bq,
                                                   const float* __restrict__ gk,
                                                   const float* __restrict__ bk,
                                                   const float* __restrict__ ctab,
                                                   const float* __restrict__ stab){
  int which = blockIdx.y;
  const short* src = qkv + (size_t)which * (NB * NH * NT * ND);
  short* dst = outp + (size_t)which * (NB * NH * NT * ND);
  const float* g = which ? gk : gq;
  const float* bb = which ? bk : bq;
  const float qs = which ? 1.0f : 0.011271055007f;   // log2(e)/128
  int wid = threadIdx.x >> 6, lane = threadIdx.x & 63;
  size_t row = (size_t)blockIdx.x * 4 + wid;  // over B*H*T
  int h = (int)((row >> 11) & 15);
  int t = (int)(row & 2047);
  const short* rp = src + row * ND;
  float v0 = bf2f(rp[lane]), v1 = bf2f(rp[lane + 64]);
  float mean = wredsum(v0 + v1) * (1.0f / 128.0f);
  float c0 = v0 - mean, c1 = v1 - mean;
  float ms = wredsum(c0 * c0 + c1 * c1) * (1.0f / 128.0f);
  float rstd = rsqrtf(ms + 1e-6f);
  float n0 = c0 * rstd * (1.0f + g[h * ND + lane]) + bb[h * ND + lane];
  float n1 = c1 * rstd * (1.0f + g[h * ND + lane + 64]) + bb[h * ND + lane + 64];
  float co = ctab[t * 64 + lane], si = stab[t * 64 + lane];
  short* wp = dst + row * ND;
  wp[lane]      = (short)f2bf((n0 * co - n1 * si) * qs);
  wp[lane + 64] = (short)f2bf((n0 * si + n1 * co) * qs);
}

// ---------------- flash attention v3: QBLK=128, 8 waves, triple-buffer -----
__global__ __launch_bounds__(512) void attn_k(const short* __restrict__ qn,
                                              const short* __restrict__ kn,
                                              const short* __restrict__ vt,
                                              short* __restrict__ ob){
  extern __shared__ char lds[];
  const int tid = threadIdx.x;
  const int wid = tid >> 6, lane = tid & 63;   // wid 0..7
  const int lrow = lane & 15, g8 = lane >> 4;
  const int id = blockIdx.x;
  const int qs = id >> 5;             // 0..7
  const int bh = id & 31;             // same-bh ids congruent mod 8 -> same XCD
  const int b = bh >> 4, h = bh & 15;
  const size_t base = (size_t)bh * NT * ND;
  char* Pw = lds + 98304 + wid * 2048;

  auto STAGE = [&](int jb){
    const int cb = jb % 3;
    #pragma unroll
    for (int i = 0; i < 2; ++i){
      int r0 = wid * 4 + i * 32;
      int r = r0 + (lane >> 4);
      int g = lane & 15;
      gload_lds16(kn + base + (size_t)(jb * 64 + r) * ND + ((g ^ (r & 7)) << 3),
                  lds + cb * 16384 + r0 * 256);
    }
    #pragma unroll
    for (int i = 0; i < 2; ++i){
      int d0 = wid * 8 + i * 64;
      int d = d0 + (lane >> 3);
      int g = lane & 7;
      gload_lds16(vt + base + (size_t)jb * 8192 + d * 64 + ((g ^ (d & 7)) << 3),
                  lds + 49152 + cb * 16384 + d0 * 128);
    }
  };

  for (int pass = 0; pass < 2; ++pass){
    const int qt = pass ? (15 - qs) : qs;      // supertile of 128 q-rows
    const int t0 = qt * 128;
    const int wrow0 = t0 + wid * 16;
    const int tq = wrow0 + lrow;
    bf16x8 qf[4];
    #pragma unroll
    for (int dc = 0; dc < 4; ++dc)
      qf[dc] = *(const bf16x8*)(qn + base + (size_t)tq * ND + dc * 32 + g8 * 8);
    f32x4 O[8] = {};
    float m = -3e38f, lsum = 0.0f;
    const int ntiles = 2 * qt + 2;

    __syncthreads();             // all reads of LDS from previous pass done
    STAGE(0);
    STAGE(1);

    for (int jb = 0; jb < ntiles; ++jb){
      if (jb + 1 < ntiles) asm volatile("s_waitcnt vmcnt(4)" ::: "memory");
      else                 asm volatile("s_waitcnt vmcnt(0)" ::: "memory");
      __builtin_amdgcn_s_barrier();          // tile jb resident
      if (jb + 2 < ntiles) STAGE(jb + 2);    // write buf (jb+2)%3: readers done
      const char* Kb = lds + (jb % 3) * 16384;
      const char* Vb = lds + 49152 + (jb % 3) * 16384;

      if (jb * 64 <= wrow0 + 15){
        f32x4 st[4] = {};
        __builtin_amdgcn_s_setprio(1);
        #pragma unroll
        for (int dc = 0; dc < 4; ++dc)
          #pragma unroll
          for (int js = 0; js < 4; ++js){
            int jl = js * 16 + lrow;
            bf16x8 kf = *(const bf16x8*)(Kb + jl * 256 +
                          (((dc * 4 + g8) ^ (jl & 7)) << 4));
            st[js] = __builtin_amdgcn_mfma_f32_16x16x32_bf16(kf, qf[dc], st[js], 0, 0, 0);
          }
        __builtin_amdgcn_s_setprio(0);
        if (jb * 64 + 63 > wrow0){
          #pragma unroll
          for (int js = 0; js < 4; ++js)
            #pragma unroll
            for (int r = 0; r < 4; ++r){
              int j = jb * 64 + js * 16 + g8 * 4 + r;
              if (j > tq) st[js][r] = -3e38f;
            }
        }
        f32x4 m4 = st[0];
        #pragma unroll
        for (int js = 1; js < 4; ++js)
          #pragma unroll
          for (int r = 0; r < 4; ++r) m4[r] = fmaxf(m4[r], st[js][r]);
        float mx = fmaxf(fmaxf(m4[0], m4[1]), fmaxf(m4[2], m4[3]));
        mx = fmaxf(mx, __shfl_xor(mx, 16));
        mx = fmaxf(mx, __shfl_xor(mx, 32));
        if (!__all(mx <= m + 8.0f)){
          float mnew = fmaxf(m, mx);
          float fac = exp2f(m - mnew);
          m = mnew;
          lsum *= fac;
          #pragma unroll
          for (int dcb = 0; dcb < 8; ++dcb) O[dcb] *= fac;
        }
        float ps = 0.0f;
        #pragma unroll
        for (int js = 0; js < 4; ++js){
          float p0 = exp2f(st[js][0] - m);
          float p1 = exp2f(st[js][1] - m);
          float p2 = exp2f(st[js][2] - m);
          float p3 = exp2f(st[js][3] - m);
          ps += (p0 + p1) + (p2 + p3);
          unsigned int lo, hi;
          asm("v_cvt_pk_bf16_f32 %0, %1, %2" : "=v"(lo) : "v"(p0), "v"(p1));
          asm("v_cvt_pk_bf16_f32 %0, %1, %2" : "=v"(hi) : "v"(p2), "v"(p3));
          uint2 w; w.x = lo; w.y = hi;
          *(uint2*)(Pw + lrow * 128 + ((js * 32 + g8 * 8) ^ ((lrow & 7) << 4))) = w;
        }
        ps += __shfl_xor(ps, 16);
        ps += __shfl_xor(ps, 32);
        lsum += ps;
        asm volatile("s_waitcnt lgkmcnt(0)" ::: "memory");
        __builtin_amdgcn_s_setprio(1);
        #pragma unroll
        for (int j32 = 0; j32 < 2; ++j32){
          bf16x8 pf = *(const bf16x8*)(Pw + lrow * 128 +
                        ((j32 * 64 + g8 * 16) ^ ((lrow & 7) << 4)));
          #pragma unroll
          for (int dcb = 0; dcb < 8; ++dcb){
            int d = dcb * 16 + lrow;
            bf16x8 vf = *(const bf16x8*)(Vb + d * 128 +
                          (((j32 * 4 + g8) ^ (d & 7)) << 4));
            O[dcb] = __builtin_amdgcn_mfma_f32_16x16x32_bf16(vf, pf, O[dcb], 0, 0, 0);
          }
        }
        __builtin_amdgcn_s_setprio(0);
      }
    }
    float inv = 1.0f / lsum;
    #pragma unroll
    for (int dcb = 0; dcb < 8; ++dcb){
      bf16x4 w4;
      #pragma unroll
      for (int r = 0; r < 4; ++r) w4[r] = (short)f2bf(O[dcb][r] * inv);
      *(bf16x4*)(ob + ((size_t)(b * NT + tq)) * (NH * ND) + h * ND + dcb * 16 + g8 * 4) = w4;
    }
  }
}

// ---------------------------------------------------------------------------
extern "C" void kernel_launch(void* const* d_in, const int* in_sizes, int n_in,
                              void* d_out, int out_size, void* d_ws, size_t ws_size,
                              hipStream_t stream){
  const float* x  = (const float*)d_in[0];
  const float* wq = (const float*)d_in[1];
  const float* wk = (const float*)d_in[2];
  const float* wv = (const float*)d_in[3];
  const float* wo = (const float*)d_in[4];
  const float* gq = (const float*)d_in[5];
  const float* bq = (const float*)d_in[6];
  const float* gk = (const float*)d_in[7];
  const float* bk = (const float*)d_in[8];

  char* ws = (char*)d_ws;
  short* xb   = (short*)(ws);                      // 16,777,216 B
  short* wT   = (short*)(ws + 16777216);           // 33,554,432 B (q,k,v,o ^T)
  short* qkvb = (short*)(ws + 50331648);           // 50,331,648 B (q|k|v^T bf16)
  short* qkn  = (short*)(ws + 100663296);          // 33,554,432 B (qn|kn)
  short* ob   = (short*)(ws + 134217728);          // 16,777,216 B
  float* ctab = (float*)(ws + 150994944);          // 524,288 B
  float* stab = (float*)(ws + 151519232);          // 524,288 B

  (void)hipFuncSetAttribute((const void*)gemm256_k,
                            hipFuncAttributeMaxDynamicSharedMemorySize, 49152);
  (void)hipFuncSetAttribute((const void*)attn_k,
                            hipFuncAttributeMaxDynamicSharedMemorySize, 114688);

  prep_k<<<dim3(25088), dim3(256), 0, stream>>>(x, wq, wk, wv, wo, xb, wT, ctab, stab);
  gemm256_k<<<dim3(768), dim3(512), 49152, stream>>>(xb, wT, qkvb);
  norm_rope_k<<<dim3(16384, 2), dim3(256), 0, stream>>>(qkvb, qkn, gq, bq, gk, bk, ctab, stab);
  attn_k<<<dim3(256), dim3(512), 114688, stream>>>(qkn, qkn + 8388608,
                                                   qkvb + 2 * (size_t)8388608, ob);
  gemm_bt_k<<<dim3(32, 16), dim3(256), 0, stream>>>(ob, wT + 3 * (size_t)4194304,
                                                    (float*)d_out, 2048);
}

// Round 13
// 272.151 us; speedup vs baseline: 1.5312x; 1.0069x over previous
//
#include <hip/hip_runtime.h>

// ---------------------------------------------------------------------------
// Fused MHA: B=2, T=2048, M=2048, H=16, D=128, causal, qk-centered-RMS-norm,
// half-split rotary, QK_SCALE = 1/D.
// Pipeline: prep (cast|transpose|rope fused) -> QKV GEMM v2 (256x128, BK=32,
// 2 blocks/CU, SW-swizzled LDS) -> norm+rope (log2e/128 in Q) -> flash attn
// v3 (QBLK=128, triple-buffer, counted vmcnt) -> out GEMM v2 (fp32 out).
// ---------------------------------------------------------------------------

#define NB 2
#define NT 2048
#define NM 2048
#define NH 16
#define ND 128

typedef __attribute__((ext_vector_type(4))) float f32x4;
typedef __attribute__((ext_vector_type(8))) short bf16x8;
typedef __attribute__((ext_vector_type(4))) short bf16x4;

#define AS1 __attribute__((address_space(1)))
#define AS3 __attribute__((address_space(3)))

// bank swizzle for 64B LDS rows: 16 consecutive rows cover each bank-quad 2x
#define SW(r) (((r) ^ ((r) >> 2)) & 3)

__device__ __forceinline__ unsigned short f2bf(float f){
  unsigned int u = __float_as_uint(f);
  u = (u + 0x7fffu + ((u >> 16) & 1u)) >> 16;   // RNE
  return (unsigned short)u;
}
__device__ __forceinline__ float bf2f(short s){
  return __uint_as_float(((unsigned int)(unsigned short)s) << 16);
}
__device__ __forceinline__ float wredsum(float v){
  #pragma unroll
  for (int m = 1; m < 64; m <<= 1) v += __shfl_xor(v, m);
  return v;
}
__device__ __forceinline__ void gload_lds16(const void* g, void* l){
  __builtin_amdgcn_global_load_lds((const AS1 void*)g, (AS3 void*)l, 16, 0, 0);
}

// ------------- fused prep: cast x | transpose weights | rope table ---------
__global__ __launch_bounds__(256) void prep_k(const float* __restrict__ x,
                                              const float* __restrict__ wq,
                                              const float* __restrict__ wk,
                                              const float* __restrict__ wv,
                                              const float* __restrict__ wo,
                                              short* __restrict__ xb,
                                              short* __restrict__ wT,
                                              float* __restrict__ ctab,
                                              float* __restrict__ stab){
  __shared__ float tl[32][33];
  const int bid = blockIdx.x, tid = threadIdx.x;
  if (bid < 8192){
    size_t gid = (size_t)bid * 256 + tid;
    float4 v = *(const float4*)(x + gid * 4);
    bf16x4 o;
    o[0] = (short)f2bf(v.x); o[1] = (short)f2bf(v.y);
    o[2] = (short)f2bf(v.z); o[3] = (short)f2bf(v.w);
    *(bf16x4*)(xb + gid * 4) = o;
  } else if (bid < 24576){
    int tb = bid - 8192;
    int z = tb >> 12, rem = tb & 4095;
    int n0 = (rem & 63) * 32, k0 = (rem >> 6) * 32;
    const float* src = (z == 0) ? wq : (z == 1) ? wk : (z == 2) ? wv : wo;
    short* dst = wT + (size_t)z * 2048 * 2048;
    int cx = tid & 31, ry = tid >> 5; // 0..7
    #pragma unroll
    for (int p = 0; p < 4; ++p)
      tl[ry + 8 * p][cx] = src[(size_t)(k0 + ry + 8 * p) * 2048 + n0 + cx];
    __syncthreads();
    #pragma unroll
    for (int p = 0; p < 4; ++p)
      dst[(size_t)(n0 + ry + 8 * p) * 2048 + k0 + cx] =
          (short)f2bf(tl[cx][ry + 8 * p]);
  } else {
    int t = (bid - 24576) * 4 + (tid >> 6);
    int i = tid & 63;
    float freq = __expf(-(float)i * (9.210340371976184f / 64.0f)); // ln(10000)
    float ang = (float)t * freq;
    ctab[t * 64 + i] = cosf(ang);
    stab[t * 64 + i] = sinf(ang);
  }
}

// ---------------------------------------------------------------------------
// QKV GEMM v2: 256x128 tile, BK=32, 8 waves (4M x 2N), 2 blocks/CU.
// SW-swizzled 64B LDS rows (2-way bank spread = free). R4 minimal-sync loop.
// ---------------------------------------------------------------------------
#define NKT2 64   // 2048 / 32
__global__ __launch_bounds__(512, 4) void gemm256_k(const short* __restrict__ A,
                                                    const short* __restrict__ Bt,
                                                    short* __restrict__ Cq){
  extern __shared__ char lds[];   // A[2][16KB] @0 | B[2][8KB] @32768
  const int tid = threadIdx.x;
  const int wid = tid >> 6, lane = tid & 63;
  const int lrow = lane & 15, g8 = lane >> 4;
  const int wm = wid >> 1, wn = wid & 1;
  const int Kdim = 2048;

  // XCD-aware bijective swizzle over 768 blocks (768 % 8 == 0)
  int bid = blockIdx.x;
  int s = (bid & 7) * 96 + (bid >> 3);
  const int bx = s & 15;        // 16 m-tiles (256 rows)
  const int by = s >> 4;        // 48 n-tiles (128 cols)
  const int m0 = bx * 256, n0 = by * 128;

  const int ar = lane >> 2;                       // row within 16-row chunk
  const int ag = (lane & 3) ^ SW(ar);             // inverse-swizzled granule
  const short* Ab = A  + (size_t)(m0 + wid * 32 + ar) * Kdim + ag * 8;
  const short* Bb = Bt + (size_t)(n0 + wid * 16 + ar) * Kdim + ag * 8;

  f32x4 acc[4][4] = {};

  auto STAGE = [&](int c, int kt){
    #pragma unroll
    for (int i = 0; i < 2; ++i)
      gload_lds16(Ab + (size_t)(i * 16) * Kdim + kt * 32,
                  lds + c * 16384 + wid * 2048 + i * 1024);
    gload_lds16(Bb + kt * 32, lds + 32768 + c * 8192 + wid * 1024);
  };
  auto ldA = [&](int c, int mi) -> bf16x8 {
    int row = wm * 64 + mi * 16 + lrow;
    return *(const bf16x8*)(lds + c * 16384 + row * 64 + ((g8 ^ SW(row)) << 4));
  };
  auto ldB = [&](int c, int ni) -> bf16x8 {
    int row = wn * 64 + ni * 16 + lrow;
    return *(const bf16x8*)(lds + 32768 + c * 8192 + row * 64 + ((g8 ^ SW(row)) << 4));
  };

  STAGE(0, 0);

  for (int kt = 0; kt < NKT2; ++kt){
    const int c = kt & 1;
    asm volatile("s_waitcnt vmcnt(0)" ::: "memory");
    __builtin_amdgcn_s_barrier();
    if (kt + 1 < NKT2) STAGE(c ^ 1, kt + 1);

    bf16x8 af[4], bfv[4];
    #pragma unroll
    for (int mi = 0; mi < 4; ++mi) af[mi] = ldA(c, mi);
    #pragma unroll
    for (int ni = 0; ni < 4; ++ni) bfv[ni] = ldB(c, ni);
    #pragma unroll
    for (int mi = 0; mi < 4; ++mi)
      #pragma unroll
      for (int ni = 0; ni < 4; ++ni)
        acc[mi][ni] = __builtin_amdgcn_mfma_f32_16x16x32_bf16(
            af[mi], bfv[ni], acc[mi][ni], 0, 0, 0);
  }

  const int tsel = by >> 4;           // 0=q, 1=k, 2=v (block-uniform)
  short* dst = Cq + (size_t)tsel * (NB * NH * NT * ND);
  if (tsel < 2){
    #pragma unroll
    for (int mi = 0; mi < 4; ++mi){
      int rowb = m0 + wm * 64 + mi * 16 + g8 * 4;
      #pragma unroll
      for (int ni = 0; ni < 4; ++ni){
        int col = n0 + wn * 64 + ni * 16 + lrow;
        int hd = col & 2047;
        int hh = hd >> 7, d = hd & 127;
        f32x4 a = acc[mi][ni];
        #pragma unroll
        for (int r = 0; r < 4; ++r){
          int bt = rowb + r;
          int b = bt >> 11, t = bt & 2047;
          dst[(((size_t)(b * NH + hh)) * NT + t) * ND + d] = (short)f2bf(a[r]);
        }
      }
    }
  } else {
    #pragma unroll
    for (int mi = 0; mi < 4; ++mi){
      int rowb = m0 + wm * 64 + mi * 16 + g8 * 4;
      int b = rowb >> 11, t0 = rowb & 2047;
      int jb = t0 >> 6, toff = t0 & 63;
      #pragma unroll
      for (int ni = 0; ni < 4; ++ni){
        int col = n0 + wn * 64 + ni * 16 + lrow;
        int hd = col & 2047;
        int hh = hd >> 7, d = hd & 127;
        f32x4 a = acc[mi][ni];
        bf16x4 w4;
        #pragma unroll
        for (int r = 0; r < 4; ++r) w4[r] = (short)f2bf(a[r]);
        *(bf16x4*)&dst[(((size_t)(b * NH + hh) * 32 + jb) * ND + d) * 64 + toff] = w4;
      }
    }
  }
}

// ---------------- out-proj GEMM v2: 256x128, BK=32, fp32 out ---------------
__global__ __launch_bounds__(512, 4) void gemmo_k(const short* __restrict__ A,
                                                  const short* __restrict__ Bt,
                                                  float* __restrict__ Cout){
  extern __shared__ char lds[];   // A[2][16KB] @0 | B[2][8KB] @32768
  const int tid = threadIdx.x;
  const int wid = tid >> 6, lane = tid & 63;
  const int lrow = lane & 15, g8 = lane >> 4;
  const int wm = wid >> 1, wn = wid & 1;
  const int Kdim = 2048;

  // bijective XCD swizzle over 256 blocks
  int bid = blockIdx.x;
  int s = (bid & 7) * 32 + (bid >> 3);
  const int bx = s & 15;        // 16 m-tiles
  const int by = s >> 4;        // 16 n-tiles
  const int m0 = bx * 256, n0 = by * 128;

  const int ar = lane >> 2;
  const int ag = (lane & 3) ^ SW(ar);
  const short* Ab = A  + (size_t)(m0 + wid * 32 + ar) * Kdim + ag * 8;
  const short* Bb = Bt + (size_t)(n0 + wid * 16 + ar) * Kdim + ag * 8;

  f32x4 acc[4][4] = {};

  auto STAGE = [&](int c, int kt){
    #pragma unroll
    for (int i = 0; i < 2; ++i)
      gload_lds16(Ab + (size_t)(i * 16) * Kdim + kt * 32,
                  lds + c * 16384 + wid * 2048 + i * 1024);
    gload_lds16(Bb + kt * 32, lds + 32768 + c * 8192 + wid * 1024);
  };
  auto ldA = [&](int c, int mi) -> bf16x8 {
    int row = wm * 64 + mi * 16 + lrow;
    return *(const bf16x8*)(lds + c * 16384 + row * 64 + ((g8 ^ SW(row)) << 4));
  };
  auto ldB = [&](int c, int ni) -> bf16x8 {
    int row = wn * 64 + ni * 16 + lrow;
    return *(const bf16x8*)(lds + 32768 + c * 8192 + row * 64 + ((g8 ^ SW(row)) << 4));
  };

  STAGE(0, 0);

  for (int kt = 0; kt < NKT2; ++kt){
    const int c = kt & 1;
    asm volatile("s_waitcnt vmcnt(0)" ::: "memory");
    __builtin_amdgcn_s_barrier();
    if (kt + 1 < NKT2) STAGE(c ^ 1, kt + 1);

    bf16x8 af[4], bfv[4];
    #pragma unroll
    for (int mi = 0; mi < 4; ++mi) af[mi] = ldA(c, mi);
    #pragma unroll
    for (int ni = 0; ni < 4; ++ni) bfv[ni] = ldB(c, ni);
    #pragma unroll
    for (int mi = 0; mi < 4; ++mi)
      #pragma unroll
      for (int ni = 0; ni < 4; ++ni)
        acc[mi][ni] = __builtin_amdgcn_mfma_f32_16x16x32_bf16(
            af[mi], bfv[ni], acc[mi][ni], 0, 0, 0);
  }

  #pragma unroll
  for (int mi = 0; mi < 4; ++mi){
    int rowb = m0 + wm * 64 + mi * 16 + g8 * 4;
    #pragma unroll
    for (int ni = 0; ni < 4; ++ni){
      int col = n0 + wn * 64 + ni * 16 + lrow;
      f32x4 a = acc[mi][ni];
      #pragma unroll
      for (int r = 0; r < 4; ++r)
        Cout[(size_t)(rowb + r) * 2048 + col] = a[r];
    }
  }
}

// -------------- centered RMS norm + rotary (q and k) -----------------------
__global__ __launch_bounds__(256) void norm_rope_k(const short* __restrict__ qkv,
                                                   short* __restrict__ outp,
                                                   const float* __restrict__ gq,
                                                   const float* __restrict__ bq,
                                                   const float* __restrict__ gk,
                                                   const float* __restrict__ bk,
                                                   const float* __restrict__ ctab,
                                                   const float* __restrict__ stab){
  int which = blockIdx.y;
  const short* src = qkv + (size_t)which * (NB * NH * NT * ND);
  short* dst = outp + (size_t)which * (NB * NH * NT * ND);
  const float* g = which ? gk : gq;
  const float* bb = which ? bk : bq;
  const float qs = which ? 1.0f : 0.011271055007f;   // log2(e)/128
  int wid = threadIdx.x >> 6, lane = threadIdx.x & 63;
  size_t row = (size_t)blockIdx.x * 4 + wid;  // over B*H*T
  int h = (int)((row >> 11) & 15);
  int t = (int)(row & 2047);
  const short* rp = src + row * ND;
  float v0 = bf2f(rp[lane]), v1 = bf2f(rp[lane + 64]);
  float mean = wredsum(v0 + v1) * (1.0f / 128.0f);
  float c0 = v0 - mean, c1 = v1 - mean;
  float ms = wredsum(c0 * c0 + c1 * c1) * (1.0f / 128.0f);
  float rstd = rsqrtf(ms + 1e-6f);
  float n0 = c0 * rstd * (1.0f + g[h * ND + lane]) + bb[h * ND + lane];
  float n1 = c1 * rstd * (1.0f + g[h * ND + lane + 64]) + bb[h * ND + lane + 64];
  float co = ctab[t * 64 + lane], si = stab[t * 64 + lane];
  short* wp = dst + row * ND;
  wp[lane]      = (short)f2bf((n0 * co - n1 * si) * qs);
  wp[lane + 64] = (short)f2bf((n0 * si + n1 * co) * qs);
}

// ---------------- flash attention v3: QBLK=128, 8 waves, triple-buffer -----
__global__ __launch_bounds__(512) void attn_k(const short* __restrict__ qn,
                                              const short* __restrict__ kn,
                                              const short* __restrict__ vt,
                                              short* __restrict__ ob){
  extern __shared__ char lds[];
  const int tid = threadIdx.x;
  const int wid = tid >> 6, lane = tid & 63;   // wid 0..7
  const int lrow = lane & 15, g8 = lane >> 4;
  const int id = blockIdx.x;
  const int qs = id >> 5;             // 0..7
  const int bh = id & 31;             // same-bh ids congruent mod 8 -> same XCD
  const int b = bh >> 4, h = bh & 15;
  const size_t base = (size_t)bh * NT * ND;
  char* Pw = lds + 98304 + wid * 2048;

  auto STAGE = [&](int jb){
    const int cb = jb % 3;
    #pragma unroll
    for (int i = 0; i < 2; ++i){
      int r0 = wid * 4 + i * 32;
      int r = r0 + (lane >> 4);
      int g = lane & 15;
      gload_lds16(kn + base + (size_t)(jb * 64 + r) * ND + ((g ^ (r & 7)) << 3),
                  lds + cb * 16384 + r0 * 256);
    }
    #pragma unroll
    for (int i = 0; i < 2; ++i){
      int d0 = wid * 8 + i * 64;
      int d = d0 + (lane >> 3);
      int g = lane & 7;
      gload_lds16(vt + base + (size_t)jb * 8192 + d * 64 + ((g ^ (d & 7)) << 3),
                  lds + 49152 + cb * 16384 + d0 * 128);
    }
  };

  for (int pass = 0; pass < 2; ++pass){
    const int qt = pass ? (15 - qs) : qs;      // supertile of 128 q-rows
    const int t0 = qt * 128;
    const int wrow0 = t0 + wid * 16;
    const int tq = wrow0 + lrow;
    bf16x8 qf[4];
    #pragma unroll
    for (int dc = 0; dc < 4; ++dc)
      qf[dc] = *(const bf16x8*)(qn + base + (size_t)tq * ND + dc * 32 + g8 * 8);
    f32x4 O[8] = {};
    float m = -3e38f, lsum = 0.0f;
    const int ntiles = 2 * qt + 2;

    __syncthreads();             // all reads of LDS from previous pass done
    STAGE(0);
    STAGE(1);

    for (int jb = 0; jb < ntiles; ++jb){
      if (jb + 1 < ntiles) asm volatile("s_waitcnt vmcnt(4)" ::: "memory");
      else                 asm volatile("s_waitcnt vmcnt(0)" ::: "memory");
      __builtin_amdgcn_s_barrier();          // tile jb resident
      if (jb + 2 < ntiles) STAGE(jb + 2);    // write buf (jb+2)%3: readers done
      const char* Kb = lds + (jb % 3) * 16384;
      const char* Vb = lds + 49152 + (jb % 3) * 16384;

      if (jb * 64 <= wrow0 + 15){
        f32x4 st[4] = {};
        __builtin_amdgcn_s_setprio(1);
        #pragma unroll
        for (int dc = 0; dc < 4; ++dc)
          #pragma unroll
          for (int js = 0; js < 4; ++js){
            int jl = js * 16 + lrow;
            bf16x8 kf = *(const bf16x8*)(Kb + jl * 256 +
                          (((dc * 4 + g8) ^ (jl & 7)) << 4));
            st[js] = __builtin_amdgcn_mfma_f32_16x16x32_bf16(kf, qf[dc], st[js], 0, 0, 0);
          }
        __builtin_amdgcn_s_setprio(0);
        if (jb * 64 + 63 > wrow0){
          #pragma unroll
          for (int js = 0; js < 4; ++js)
            #pragma unroll
            for (int r = 0; r < 4; ++r){
              int j = jb * 64 + js * 16 + g8 * 4 + r;
              if (j > tq) st[js][r] = -3e38f;
            }
        }
        f32x4 m4 = st[0];
        #pragma unroll
        for (int js = 1; js < 4; ++js)
          #pragma unroll
          for (int r = 0; r < 4; ++r) m4[r] = fmaxf(m4[r], st[js][r]);
        float mx = fmaxf(fmaxf(m4[0], m4[1]), fmaxf(m4[2], m4[3]));
        mx = fmaxf(mx, __shfl_xor(mx, 16));
        mx = fmaxf(mx, __shfl_xor(mx, 32));
        if (!__all(mx <= m + 8.0f)){
          float mnew = fmaxf(m, mx);
          float fac = exp2f(m - mnew);
          m = mnew;
          lsum *= fac;
          #pragma unroll
          for (int dcb = 0; dcb < 8; ++dcb) O[dcb] *= fac;
        }
        float ps = 0.0f;
        #pragma unroll
        for (int js = 0; js < 4; ++js){
          float p0 = exp2f(st[js][0] - m);
          float p1 = exp2f(st[js][1] - m);
          float p2 = exp2f(st[js][2] - m);
          float p3 = exp2f(st[js][3] - m);
          ps += (p0 + p1) + (p2 + p3);
          unsigned int lo, hi;
          asm("v_cvt_pk_bf16_f32 %0, %1, %2" : "=v"(lo) : "v"(p0), "v"(p1));
          asm("v_cvt_pk_bf16_f32 %0, %1, %2" : "=v"(hi) : "v"(p2), "v"(p3));
          uint2 w; w.x = lo; w.y = hi;
          *(uint2*)(Pw + lrow * 128 + ((js * 32 + g8 * 8) ^ ((lrow & 7) << 4))) = w;
        }
        ps += __shfl_xor(ps, 16);
        ps += __shfl_xor(ps, 32);
        lsum += ps;
        asm volatile("s_waitcnt lgkmcnt(0)" ::: "memory");
        __builtin_amdgcn_s_setprio(1);
        #pragma unroll
        for (int j32 = 0; j32 < 2; ++j32){
          bf16x8 pf = *(const bf16x8*)(Pw + lrow * 128 +
                        ((j32 * 64 + g8 * 16) ^ ((lrow & 7) << 4)));
          #pragma unroll
          for (int dcb = 0; dcb < 8; ++dcb){
            int d = dcb * 16 + lrow;
            bf16x8 vf = *(const bf16x8*)(Vb + d * 128 +
                          (((j32 * 4 + g8) ^ (d & 7)) << 4));
            O[dcb] = __builtin_amdgcn_mfma_f32_16x16x32_bf16(vf, pf, O[dcb], 0, 0, 0);
          }
        }
        __builtin_amdgcn_s_setprio(0);
      }
    }
    float inv = 1.0f / lsum;
    #pragma unroll
    for (int dcb = 0; dcb < 8; ++dcb){
      bf16x4 w4;
      #pragma unroll
      for (int r = 0; r < 4; ++r) w4[r] = (short)f2bf(O[dcb][r] * inv);
      *(bf16x4*)(ob + ((size_t)(b * NT + tq)) * (NH * ND) + h * ND + dcb * 16 + g8 * 4) = w4;
    }
  }
}

// ---------------------------------------------------------------------------
extern "C" void kernel_launch(void* const* d_in, const int* in_sizes, int n_in,
                              void* d_out, int out_size, void* d_ws, size_t ws_size,
                              hipStream_t stream){
  const float* x  = (const float*)d_in[0];
  const float* wq = (const float*)d_in[1];
  const float* wk = (const float*)d_in[2];
  const float* wv = (const float*)d_in[3];
  const float* wo = (const float*)d_in[4];
  const float* gq = (const float*)d_in[5];
  const float* bq = (const float*)d_in[6];
  const float* gk = (const float*)d_in[7];
  const float* bk = (const float*)d_in[8];

  char* ws = (char*)d_ws;
  short* xb   = (short*)(ws);                      // 16,777,216 B
  short* wT   = (short*)(ws + 16777216);           // 33,554,432 B (q,k,v,o ^T)
  short* qkvb = (short*)(ws + 50331648);           // 50,331,648 B (q|k|v^T bf16)
  short* qkn  = (short*)(ws + 100663296);          // 33,554,432 B (qn|kn)
  short* ob   = (short*)(ws + 134217728);          // 16,777,216 B
  float* ctab = (float*)(ws + 150994944);          // 524,288 B
  float* stab = (float*)(ws + 151519232);          // 524,288 B

  (void)hipFuncSetAttribute((const void*)gemm256_k,
                            hipFuncAttributeMaxDynamicSharedMemorySize, 49152);
  (void)hipFuncSetAttribute((const void*)gemmo_k,
                            hipFuncAttributeMaxDynamicSharedMemorySize, 49152);
  (void)hipFuncSetAttribute((const void*)attn_k,
                            hipFuncAttributeMaxDynamicSharedMemorySize, 114688);

  prep_k<<<dim3(25088), dim3(256), 0, stream>>>(x, wq, wk, wv, wo, xb, wT, ctab, stab);
  gemm256_k<<<dim3(768), dim3(512), 49152, stream>>>(xb, wT, qkvb);
  norm_rope_k<<<dim3(16384, 2), dim3(256), 0, stream>>>(qkvb, qkn, gq, bq, gk, bk, ctab, stab);
  attn_k<<<dim3(256), dim3(512), 114688, stream>>>(qkn, qkn + 8388608,
                                                   qkvb + 2 * (size_t)8388608, ob);
  gemmo_k<<<dim3(256), dim3(512), 49152, stream>>>(ob, wT + 3 * (size_t)4194304,
                                                   (float*)d_out);
}

// Round 14
// 262.484 us; speedup vs baseline: 1.5876x; 1.0368x over previous
//
#include <hip/hip_runtime.h>

// ---------------------------------------------------------------------------
// Fused MHA: B=2, T=2048, M=2048, H=16, D=128, causal, qk-centered-RMS-norm,
// half-split rotary, QK_SCALE = 1/D.
// Pipeline: prep (cast|transpose|rope fused) -> QKV GEMM v2 (256x128, BK=32,
// 2 blocks/CU; q/k epilogue FUSES centered-RMS + rope + log2e/128 scale;
// V tile-transposed) -> flash attn v3 -> out GEMM v2 (fp32 out).
// ---------------------------------------------------------------------------

#define NB 2
#define NT 2048
#define NM 2048
#define NH 16
#define ND 128

typedef __attribute__((ext_vector_type(4))) float f32x4;
typedef __attribute__((ext_vector_type(8))) short bf16x8;
typedef __attribute__((ext_vector_type(4))) short bf16x4;

#define AS1 __attribute__((address_space(1)))
#define AS3 __attribute__((address_space(3)))

#define SW(r) (((r) ^ ((r) >> 2)) & 3)

__device__ __forceinline__ unsigned short f2bf(float f){
  unsigned int u = __float_as_uint(f);
  u = (u + 0x7fffu + ((u >> 16) & 1u)) >> 16;   // RNE
  return (unsigned short)u;
}
__device__ __forceinline__ float bf2f(short s){
  return __uint_as_float(((unsigned int)(unsigned short)s) << 16);
}
__device__ __forceinline__ void gload_lds16(const void* g, void* l){
  __builtin_amdgcn_global_load_lds((const AS1 void*)g, (AS3 void*)l, 16, 0, 0);
}

// ------------- fused prep: cast x | transpose weights | rope table ---------
__global__ __launch_bounds__(256) void prep_k(const float* __restrict__ x,
                                              const float* __restrict__ wq,
                                              const float* __restrict__ wk,
                                              const float* __restrict__ wv,
                                              const float* __restrict__ wo,
                                              short* __restrict__ xb,
                                              short* __restrict__ wT,
                                              float* __restrict__ ctab,
                                              float* __restrict__ stab){
  __shared__ float tl[32][33];
  const int bid = blockIdx.x, tid = threadIdx.x;
  if (bid < 8192){
    size_t gid = (size_t)bid * 256 + tid;
    float4 v = *(const float4*)(x + gid * 4);
    bf16x4 o;
    o[0] = (short)f2bf(v.x); o[1] = (short)f2bf(v.y);
    o[2] = (short)f2bf(v.z); o[3] = (short)f2bf(v.w);
    *(bf16x4*)(xb + gid * 4) = o;
  } else if (bid < 24576){
    int tb = bid - 8192;
    int z = tb >> 12, rem = tb & 4095;
    int n0 = (rem & 63) * 32, k0 = (rem >> 6) * 32;
    const float* src = (z == 0) ? wq : (z == 1) ? wk : (z == 2) ? wv : wo;
    short* dst = wT + (size_t)z * 2048 * 2048;
    int cx = tid & 31, ry = tid >> 5; // 0..7
    #pragma unroll
    for (int p = 0; p < 4; ++p)
      tl[ry + 8 * p][cx] = src[(size_t)(k0 + ry + 8 * p) * 2048 + n0 + cx];
    __syncthreads();
    #pragma unroll
    for (int p = 0; p < 4; ++p)
      dst[(size_t)(n0 + ry + 8 * p) * 2048 + k0 + cx] =
          (short)f2bf(tl[cx][ry + 8 * p]);
  } else {
    int t = (bid - 24576) * 4 + (tid >> 6);
    int i = tid & 63;
    float freq = __expf(-(float)i * (9.210340371976184f / 64.0f)); // ln(10000)
    float ang = (float)t * freq;
    ctab[t * 64 + i] = cosf(ang);
    stab[t * 64 + i] = sinf(ang);
  }
}

// ---------------------------------------------------------------------------
// QKV GEMM v2: 256x128 tile, BK=32, 8 waves (4M x 2N), 2 blocks/CU.
// Fused q/k epilogue: centered-RMS (f32-exact) + rope + log2e/128 scale,
// written directly to qn|kn. V written tile-transposed to vt.
// LDS: main loop 48KB; epilogue red[256][4]f32 @0 + xch[256][136]bf16 @4096.
// ---------------------------------------------------------------------------
#define NKT2 64   // 2048 / 32
__global__ __launch_bounds__(512, 4) void gemm256_k(const short* __restrict__ A,
                                                    const short* __restrict__ Bt,
                                                    short* __restrict__ Cq,
                                                    short* __restrict__ Cn,
                                                    const float* __restrict__ gq,
                                                    const float* __restrict__ bq,
                                                    const float* __restrict__ gk,
                                                    const float* __restrict__ bk,
                                                    const float* __restrict__ ctab,
                                                    const float* __restrict__ stab){
  extern __shared__ char lds[];   // A[2][16KB] @0 | B[2][8KB] @32768
  const int tid = threadIdx.x;
  const int wid = tid >> 6, lane = tid & 63;
  const int lrow = lane & 15, g8 = lane >> 4;
  const int wm = wid >> 1, wn = wid & 1;
  const int Kdim = 2048;

  // XCD-aware bijective swizzle over 768 blocks (768 % 8 == 0)
  int bid = blockIdx.x;
  int s = (bid & 7) * 96 + (bid >> 3);
  const int bx = s & 15;        // 16 m-tiles (256 rows)
  const int by = s >> 4;        // 48 n-tiles (128 cols)
  const int m0 = bx * 256, n0 = by * 128;

  const int ar = lane >> 2;
  const int ag = (lane & 3) ^ SW(ar);
  const short* Ab = A  + (size_t)(m0 + wid * 32 + ar) * Kdim + ag * 8;
  const short* Bb = Bt + (size_t)(n0 + wid * 16 + ar) * Kdim + ag * 8;

  f32x4 acc[4][4] = {};

  auto STAGE = [&](int c, int kt){
    #pragma unroll
    for (int i = 0; i < 2; ++i)
      gload_lds16(Ab + (size_t)(i * 16) * Kdim + kt * 32,
                  lds + c * 16384 + wid * 2048 + i * 1024);
    gload_lds16(Bb + kt * 32, lds + 32768 + c * 8192 + wid * 1024);
  };
  auto ldA = [&](int c, int mi) -> bf16x8 {
    int row = wm * 64 + mi * 16 + lrow;
    return *(const bf16x8*)(lds + c * 16384 + row * 64 + ((g8 ^ SW(row)) << 4));
  };
  auto ldB = [&](int c, int ni) -> bf16x8 {
    int row = wn * 64 + ni * 16 + lrow;
    return *(const bf16x8*)(lds + 32768 + c * 8192 + row * 64 + ((g8 ^ SW(row)) << 4));
  };

  STAGE(0, 0);

  for (int kt = 0; kt < NKT2; ++kt){
    const int c = kt & 1;
    asm volatile("s_waitcnt vmcnt(0)" ::: "memory");
    __builtin_amdgcn_s_barrier();
    if (kt + 1 < NKT2) STAGE(c ^ 1, kt + 1);

    bf16x8 af[4], bfv[4];
    #pragma unroll
    for (int mi = 0; mi < 4; ++mi) af[mi] = ldA(c, mi);
    #pragma unroll
    for (int ni = 0; ni < 4; ++ni) bfv[ni] = ldB(c, ni);
    #pragma unroll
    for (int mi = 0; mi < 4; ++mi)
      #pragma unroll
      for (int ni = 0; ni < 4; ++ni)
        acc[mi][ni] = __builtin_amdgcn_mfma_f32_16x16x32_bf16(
            af[mi], bfv[ni], acc[mi][ni], 0, 0, 0);
  }

  const int tsel = by >> 4;           // 0=q, 1=k, 2=v (block-uniform)
  const int hh = by & 15;             // single head per tile
  if (tsel < 2){
    // ---- fused centered-RMS + rope epilogue ----
    const float* gv = tsel ? gk : gq;
    const float* bv = tsel ? bk : bq;
    float* red = (float*)lds;               // [256][2wn][2] partials
    short* xch = (short*)(lds + 4096);      // [256][136] bf16 (row pad: 272B)
    __syncthreads();                        // main-loop LDS dead
    #pragma unroll
    for (int mi = 0; mi < 4; ++mi)
      #pragma unroll
      for (int r = 0; r < 4; ++r){
        float a0 = acc[mi][0][r], a1 = acc[mi][1][r];
        float a2 = acc[mi][2][r], a3 = acc[mi][3][r];
        float s1 = (a0 + a1) + (a2 + a3);
        float s2 = (a0*a0 + a1*a1) + (a2*a2 + a3*a3);
        #pragma unroll
        for (int off = 1; off < 16; off <<= 1){
          s1 += __shfl_xor(s1, off);
          s2 += __shfl_xor(s2, off);
        }
        if (lrow == 0){
          int row = wm * 64 + mi * 16 + g8 * 4 + r;
          red[row * 4 + wn * 2]     = s1;
          red[row * 4 + wn * 2 + 1] = s2;
        }
      }
    __syncthreads();
    #pragma unroll
    for (int mi = 0; mi < 4; ++mi)
      #pragma unroll
      for (int r = 0; r < 4; ++r){
        int row = wm * 64 + mi * 16 + g8 * 4 + r;
        float s1 = red[row * 4] + red[row * 4 + 2];
        float s2 = red[row * 4 + 1] + red[row * 4 + 3];
        float mean = s1 * (1.0f / 128.0f);
        float var = s2 * (1.0f / 128.0f) - mean * mean;
        float rstd = rsqrtf(var + 1e-6f);
        #pragma unroll
        for (int ni = 0; ni < 4; ++ni){
          int d = wn * 64 + ni * 16 + lrow;
          float n = (acc[mi][ni][r] - mean) * rstd * (1.0f + gv[hh * 128 + d])
                    + bv[hh * 128 + d];
          acc[mi][ni][r] = n;
          xch[row * 136 + d] = (short)f2bf(n);
        }
      }
    __syncthreads();
    const float sgn = wn ? 1.0f : -1.0f;
    const float qsc = tsel ? 1.0f : 0.011271055007f;   // log2(e)/128 on q
    short* dstn = Cn + (size_t)tsel * (NB * NH * NT * ND);
    #pragma unroll
    for (int mi = 0; mi < 4; ++mi)
      #pragma unroll
      for (int r = 0; r < 4; ++r){
        int rowb = m0 + wm * 64 + mi * 16 + g8 * 4 + r;
        int b = rowb >> 11, t = rowb & 2047;
        int row = rowb - m0;
        #pragma unroll
        for (int ni = 0; ni < 4; ++ni){
          int d = wn * 64 + ni * 16 + lrow;
          int dl = ni * 16 + lrow;
          float pv = bf2f(xch[row * 136 + (d ^ 64)]);
          float c = ctab[t * 64 + dl], sn = stab[t * 64 + dl];
          float o = (acc[mi][ni][r] * c + sgn * pv * sn) * qsc;
          dstn[(((size_t)(b * NH + hh)) * NT + t) * ND + d] = (short)f2bf(o);
        }
      }
  } else {
    short* dst = Cq + 2 * (size_t)(NB * NH * NT * ND);
    #pragma unroll
    for (int mi = 0; mi < 4; ++mi){
      int rowb = m0 + wm * 64 + mi * 16 + g8 * 4;
      int b = rowb >> 11, t0 = rowb & 2047;
      int jb = t0 >> 6, toff = t0 & 63;
      #pragma unroll
      for (int ni = 0; ni < 4; ++ni){
        int d = wn * 64 + ni * 16 + lrow;
        f32x4 a = acc[mi][ni];
        bf16x4 w4;
        #pragma unroll
        for (int r = 0; r < 4; ++r) w4[r] = (short)f2bf(a[r]);
        *(bf16x4*)&dst[(((size_t)(b * NH + hh) * 32 + jb) * ND + d) * 64 + toff] = w4;
      }
    }
  }
}

// ---------------- out-proj GEMM v2: 256x128, BK=32, fp32 out ---------------
__global__ __launch_bounds__(512, 4) void gemmo_k(const short* __restrict__ A,
                                                  const short* __restrict__ Bt,
                                                  float* __restrict__ Cout){
  extern __shared__ char lds[];
  const int tid = threadIdx.x;
  const int wid = tid >> 6, lane = tid & 63;
  const int lrow = lane & 15, g8 = lane >> 4;
  const int wm = wid >> 1, wn = wid & 1;
  const int Kdim = 2048;

  int bid = blockIdx.x;
  int s = (bid & 7) * 32 + (bid >> 3);
  const int bx = s & 15;
  const int by = s >> 4;
  const int m0 = bx * 256, n0 = by * 128;

  const int ar = lane >> 2;
  const int ag = (lane & 3) ^ SW(ar);
  const short* Ab = A  + (size_t)(m0 + wid * 32 + ar) * Kdim + ag * 8;
  const short* Bb = Bt + (size_t)(n0 + wid * 16 + ar) * Kdim + ag * 8;

  f32x4 acc[4][4] = {};

  auto STAGE = [&](int c, int kt){
    #pragma unroll
    for (int i = 0; i < 2; ++i)
      gload_lds16(Ab + (size_t)(i * 16) * Kdim + kt * 32,
                  lds + c * 16384 + wid * 2048 + i * 1024);
    gload_lds16(Bb + kt * 32, lds + 32768 + c * 8192 + wid * 1024);
  };
  auto ldA = [&](int c, int mi) -> bf16x8 {
    int row = wm * 64 + mi * 16 + lrow;
    return *(const bf16x8*)(lds + c * 16384 + row * 64 + ((g8 ^ SW(row)) << 4));
  };
  auto ldB = [&](int c, int ni) -> bf16x8 {
    int row = wn * 64 + ni * 16 + lrow;
    return *(const bf16x8*)(lds + 32768 + c * 8192 + row * 64 + ((g8 ^ SW(row)) << 4));
  };

  STAGE(0, 0);

  for (int kt = 0; kt < NKT2; ++kt){
    const int c = kt & 1;
    asm volatile("s_waitcnt vmcnt(0)" ::: "memory");
    __builtin_amdgcn_s_barrier();
    if (kt + 1 < NKT2) STAGE(c ^ 1, kt + 1);

    bf16x8 af[4], bfv[4];
    #pragma unroll
    for (int mi = 0; mi < 4; ++mi) af[mi] = ldA(c, mi);
    #pragma unroll
    for (int ni = 0; ni < 4; ++ni) bfv[ni] = ldB(c, ni);
    #pragma unroll
    for (int mi = 0; mi < 4; ++mi)
      #pragma unroll
      for (int ni = 0; ni < 4; ++ni)
        acc[mi][ni] = __builtin_amdgcn_mfma_f32_16x16x32_bf16(
            af[mi], bfv[ni], acc[mi][ni], 0, 0, 0);
  }

  #pragma unroll
  for (int mi = 0; mi < 4; ++mi){
    int rowb = m0 + wm * 64 + mi * 16 + g8 * 4;
    #pragma unroll
    for (int ni = 0; ni < 4; ++ni){
      int col = n0 + wn * 64 + ni * 16 + lrow;
      f32x4 a = acc[mi][ni];
      #pragma unroll
      for (int r = 0; r < 4; ++r)
        Cout[(size_t)(rowb + r) * 2048 + col] = a[r];
    }
  }
}

// ---------------- flash attention v3: QBLK=128, 8 waves, triple-buffer -----
__global__ __launch_bounds__(512) void attn_k(const short* __restrict__ qn,
                                              const short* __restrict__ kn,
                                              const short* __restrict__ vt,
                                              short* __restrict__ ob){
  extern __shared__ char lds[];
  const int tid = threadIdx.x;
  const int wid = tid >> 6, lane = tid & 63;   // wid 0..7
  const int lrow = lane & 15, g8 = lane >> 4;
  const int id = blockIdx.x;
  const int qs = id >> 5;             // 0..7
  const int bh = id & 31;             // same-bh ids congruent mod 8 -> same XCD
  const int b = bh >> 4, h = bh & 15;
  const size_t base = (size_t)bh * NT * ND;
  char* Pw = lds + 98304 + wid * 2048;

  auto STAGE = [&](int jb){
    const int cb = jb % 3;
    #pragma unroll
    for (int i = 0; i < 2; ++i){
      int r0 = wid * 4 + i * 32;
      int r = r0 + (lane >> 4);
      int g = lane & 15;
      gload_lds16(kn + base + (size_t)(jb * 64 + r) * ND + ((g ^ (r & 7)) << 3),
                  lds + cb * 16384 + r0 * 256);
    }
    #pragma unroll
    for (int i = 0; i < 2; ++i){
      int d0 = wid * 8 + i * 64;
      int d = d0 + (lane >> 3);
      int g = lane & 7;
      gload_lds16(vt + base + (size_t)jb * 8192 + d * 64 + ((g ^ (d & 7)) << 3),
                  lds + 49152 + cb * 16384 + d0 * 128);
    }
  };

  for (int pass = 0; pass < 2; ++pass){
    const int qt = pass ? (15 - qs) : qs;      // supertile of 128 q-rows
    const int t0 = qt * 128;
    const int wrow0 = t0 + wid * 16;
    const int tq = wrow0 + lrow;
    bf16x8 qf[4];
    #pragma unroll
    for (int dc = 0; dc < 4; ++dc)
      qf[dc] = *(const bf16x8*)(qn + base + (size_t)tq * ND + dc * 32 + g8 * 8);
    f32x4 O[8] = {};
    float m = -3e38f, lsum = 0.0f;
    const int ntiles = 2 * qt + 2;

    __syncthreads();             // all reads of LDS from previous pass done
    STAGE(0);
    STAGE(1);

    for (int jb = 0; jb < ntiles; ++jb){
      if (jb + 1 < ntiles) asm volatile("s_waitcnt vmcnt(4)" ::: "memory");
      else                 asm volatile("s_waitcnt vmcnt(0)" ::: "memory");
      __builtin_amdgcn_s_barrier();          // tile jb resident
      if (jb + 2 < ntiles) STAGE(jb + 2);    // write buf (jb+2)%3: readers done
      const char* Kb = lds + (jb % 3) * 16384;
      const char* Vb = lds + 49152 + (jb % 3) * 16384;

      if (jb * 64 <= wrow0 + 15){
        f32x4 st[4] = {};
        __builtin_amdgcn_s_setprio(1);
        #pragma unroll
        for (int dc = 0; dc < 4; ++dc)
          #pragma unroll
          for (int js = 0; js < 4; ++js){
            int jl = js * 16 + lrow;
            bf16x8 kf = *(const bf16x8*)(Kb + jl * 256 +
                          (((dc * 4 + g8) ^ (jl & 7)) << 4));
            st[js] = __builtin_amdgcn_mfma_f32_16x16x32_bf16(kf, qf[dc], st[js], 0, 0, 0);
          }
        __builtin_amdgcn_s_setprio(0);
        if (jb * 64 + 63 > wrow0){
          #pragma unroll
          for (int js = 0; js < 4; ++js)
            #pragma unroll
            for (int r = 0; r < 4; ++r){
              int j = jb * 64 + js * 16 + g8 * 4 + r;
              if (j > tq) st[js][r] = -3e38f;
            }
        }
        f32x4 m4 = st[0];
        #pragma unroll
        for (int js = 1; js < 4; ++js)
          #pragma unroll
          for (int r = 0; r < 4; ++r) m4[r] = fmaxf(m4[r], st[js][r]);
        float mx = fmaxf(fmaxf(m4[0], m4[1]), fmaxf(m4[2], m4[3]));
        mx = fmaxf(mx, __shfl_xor(mx, 16));
        mx = fmaxf(mx, __shfl_xor(mx, 32));
        if (!__all(mx <= m + 8.0f)){
          float mnew = fmaxf(m, mx);
          float fac = exp2f(m - mnew);
          m = mnew;
          lsum *= fac;
          #pragma unroll
          for (int dcb = 0; dcb < 8; ++dcb) O[dcb] *= fac;
        }
        float ps = 0.0f;
        #pragma unroll
        for (int js = 0; js < 4; ++js){
          float p0 = exp2f(st[js][0] - m);
          float p1 = exp2f(st[js][1] - m);
          float p2 = exp2f(st[js][2] - m);
          float p3 = exp2f(st[js][3] - m);
          ps += (p0 + p1) + (p2 + p3);
          unsigned int lo, hi;
          asm("v_cvt_pk_bf16_f32 %0, %1, %2" : "=v"(lo) : "v"(p0), "v"(p1));
          asm("v_cvt_pk_bf16_f32 %0, %1, %2" : "=v"(hi) : "v"(p2), "v"(p3));
          uint2 w; w.x = lo; w.y = hi;
          *(uint2*)(Pw + lrow * 128 + ((js * 32 + g8 * 8) ^ ((lrow & 7) << 4))) = w;
        }
        ps += __shfl_xor(ps, 16);
        ps += __shfl_xor(ps, 32);
        lsum += ps;
        asm volatile("s_waitcnt lgkmcnt(0)" ::: "memory");
        __builtin_amdgcn_s_setprio(1);
        #pragma unroll
        for (int j32 = 0; j32 < 2; ++j32){
          bf16x8 pf = *(const bf16x8*)(Pw + lrow * 128 +
                        ((j32 * 64 + g8 * 16) ^ ((lrow & 7) << 4)));
          #pragma unroll
          for (int dcb = 0; dcb < 8; ++dcb){
            int d = dcb * 16 + lrow;
            bf16x8 vf = *(const bf16x8*)(Vb + d * 128 +
                          (((j32 * 4 + g8) ^ (d & 7)) << 4));
            O[dcb] = __builtin_amdgcn_mfma_f32_16x16x32_bf16(vf, pf, O[dcb], 0, 0, 0);
          }
        }
        __builtin_amdgcn_s_setprio(0);
      }
    }
    float inv = 1.0f / lsum;
    #pragma unroll
    for (int dcb = 0; dcb < 8; ++dcb){
      bf16x4 w4;
      #pragma unroll
      for (int r = 0; r < 4; ++r) w4[r] = (short)f2bf(O[dcb][r] * inv);
      *(bf16x4*)(ob + ((size_t)(b * NT + tq)) * (NH * ND) + h * ND + dcb * 16 + g8 * 4) = w4;
    }
  }
}

// ---------------------------------------------------------------------------
extern "C" void kernel_launch(void* const* d_in, const int* in_sizes, int n_in,
                              void* d_out, int out_size, void* d_ws, size_t ws_size,
                              hipStream_t stream){
  const float* x  = (const float*)d_in[0];
  const float* wq = (const float*)d_in[1];
  const float* wk = (const float*)d_in[2];
  const float* wv = (const float*)d_in[3];
  const float* wo = (const float*)d_in[4];
  const float* gq = (const float*)d_in[5];
  const float* bq = (const float*)d_in[6];
  const float* gk = (const float*)d_in[7];
  const float* bk = (const float*)d_in[8];

  char* ws = (char*)d_ws;
  short* xb   = (short*)(ws);                      // 16,777,216 B
  short* wT   = (short*)(ws + 16777216);           // 33,554,432 B (q,k,v,o ^T)
  short* qkvb = (short*)(ws + 50331648);           // 50,331,648 B (v^T region used)
  short* qkn  = (short*)(ws + 100663296);          // 33,554,432 B (qn|kn)
  short* ob   = (short*)(ws + 134217728);          // 16,777,216 B
  float* ctab = (float*)(ws + 150994944);          // 524,288 B
  float* stab = (float*)(ws + 151519232);          // 524,288 B

  (void)hipFuncSetAttribute((const void*)gemm256_k,
                            hipFuncAttributeMaxDynamicSharedMemorySize, 73728);
  (void)hipFuncSetAttribute((const void*)gemmo_k,
                            hipFuncAttributeMaxDynamicSharedMemorySize, 49152);
  (void)hipFuncSetAttribute((const void*)attn_k,
                            hipFuncAttributeMaxDynamicSharedMemorySize, 114688);

  prep_k<<<dim3(25088), dim3(256), 0, stream>>>(x, wq, wk, wv, wo, xb, wT, ctab, stab);
  gemm256_k<<<dim3(768), dim3(512), 73728, stream>>>(xb, wT, qkvb, qkn,
                                                     gq, bq, gk, bk, ctab, stab);
  attn_k<<<dim3(256), dim3(512), 114688, stream>>>(qkn, qkn + 8388608,
                                                   qkvb + 2 * (size_t)8388608, ob);
  gemmo_k<<<dim3(256), dim3(512), 49152, stream>>>(ob, wT + 3 * (size_t)4194304,
                                                   (float*)d_out);
}

// Round 15
// 256.949 us; speedup vs baseline: 1.6218x; 1.0215x over previous
//
#include <hip/hip_runtime.h>

// ---------------------------------------------------------------------------
// Fused MHA: B=2, T=2048, M=2048, H=16, D=128, causal, qk-centered-RMS-norm,
// half-split rotary, QK_SCALE = 1/D.
// Pipeline: prep (cast|transpose|rope fused) -> QKV GEMM v3 (256x128, BK=32,
// waves tile M only: 32 rows x 128 cols each -> register-only fused
// norm+rope epilogue) -> flash attn v3 -> out GEMM v2 (fp32 out).
// ---------------------------------------------------------------------------

#define NB 2
#define NT 2048
#define NM 2048
#define NH 16
#define ND 128

typedef __attribute__((ext_vector_type(4))) float f32x4;
typedef __attribute__((ext_vector_type(8))) short bf16x8;
typedef __attribute__((ext_vector_type(4))) short bf16x4;

#define AS1 __attribute__((address_space(1)))
#define AS3 __attribute__((address_space(3)))

#define SW(r) (((r) ^ ((r) >> 2)) & 3)

__device__ __forceinline__ unsigned short f2bf(float f){
  unsigned int u = __float_as_uint(f);
  u = (u + 0x7fffu + ((u >> 16) & 1u)) >> 16;   // RNE
  return (unsigned short)u;
}
__device__ __forceinline__ float bf2f(short s){
  return __uint_as_float(((unsigned int)(unsigned short)s) << 16);
}
__device__ __forceinline__ void gload_lds16(const void* g, void* l){
  __builtin_amdgcn_global_load_lds((const AS1 void*)g, (AS3 void*)l, 16, 0, 0);
}

// ------------- fused prep: cast x | transpose weights | rope table ---------
__global__ __launch_bounds__(256) void prep_k(const float* __restrict__ x,
                                              const float* __restrict__ wq,
                                              const float* __restrict__ wk,
                                              const float* __restrict__ wv,
                                              const float* __restrict__ wo,
                                              short* __restrict__ xb,
                                              short* __restrict__ wT,
                                              float* __restrict__ ctab,
                                              float* __restrict__ stab){
  __shared__ float tl[32][33];
  const int bid = blockIdx.x, tid = threadIdx.x;
  if (bid < 8192){
    size_t gid = (size_t)bid * 256 + tid;
    float4 v = *(const float4*)(x + gid * 4);
    bf16x4 o;
    o[0] = (short)f2bf(v.x); o[1] = (short)f2bf(v.y);
    o[2] = (short)f2bf(v.z); o[3] = (short)f2bf(v.w);
    *(bf16x4*)(xb + gid * 4) = o;
  } else if (bid < 24576){
    int tb = bid - 8192;
    int z = tb >> 12, rem = tb & 4095;
    int n0 = (rem & 63) * 32, k0 = (rem >> 6) * 32;
    const float* src = (z == 0) ? wq : (z == 1) ? wk : (z == 2) ? wv : wo;
    short* dst = wT + (size_t)z * 2048 * 2048;
    int cx = tid & 31, ry = tid >> 5; // 0..7
    #pragma unroll
    for (int p = 0; p < 4; ++p)
      tl[ry + 8 * p][cx] = src[(size_t)(k0 + ry + 8 * p) * 2048 + n0 + cx];
    __syncthreads();
    #pragma unroll
    for (int p = 0; p < 4; ++p)
      dst[(size_t)(n0 + ry + 8 * p) * 2048 + k0 + cx] =
          (short)f2bf(tl[cx][ry + 8 * p]);
  } else {
    int t = (bid - 24576) * 4 + (tid >> 6);
    int i = tid & 63;
    float freq = __expf(-(float)i * (9.210340371976184f / 64.0f)); // ln(10000)
    float ang = (float)t * freq;
    ctab[t * 64 + i] = cosf(ang);
    stab[t * 64 + i] = sinf(ang);
  }
}

// ---------------------------------------------------------------------------
// QKV GEMM v3: 256x128 tile, BK=32, 8 waves x (32 rows x 128 cols), 512 thr,
// 48 KiB LDS, 2 blocks/CU. Each lane holds full d-range of its rows ->
// register-only centered-RMS + rope + log2e/128 epilogue (no LDS, no syncs).
// V written tile-transposed.
// ---------------------------------------------------------------------------
#define NKT2 64   // 2048 / 32
__global__ __launch_bounds__(512, 4) void gemm256_k(const short* __restrict__ A,
                                                    const short* __restrict__ Bt,
                                                    short* __restrict__ Cv,
                                                    short* __restrict__ Cn,
                                                    const float* __restrict__ gq,
                                                    const float* __restrict__ bq,
                                                    const float* __restrict__ gk,
                                                    const float* __restrict__ bk,
                                                    const float* __restrict__ ctab,
                                                    const float* __restrict__ stab){
  extern __shared__ char lds[];   // A[2][16KB] @0 | B[2][8KB] @32768
  const int tid = threadIdx.x;
  const int wid = tid >> 6, lane = tid & 63;
  const int lrow = lane & 15, g8 = lane >> 4;
  const int Kdim = 2048;

  // XCD-aware bijective swizzle over 768 blocks (768 % 8 == 0)
  int bid = blockIdx.x;
  int s = (bid & 7) * 96 + (bid >> 3);
  const int bx = s & 15;        // 16 m-tiles (256 rows)
  const int by = s >> 4;        // 48 n-tiles (128 cols)
  const int m0 = bx * 256, n0 = by * 128;

  const int ar = lane >> 2;
  const int ag = (lane & 3) ^ SW(ar);
  const short* Ab = A  + (size_t)(m0 + wid * 32 + ar) * Kdim + ag * 8;
  const short* Bb = Bt + (size_t)(n0 + wid * 16 + ar) * Kdim + ag * 8;

  f32x4 acc[2][8] = {};

  auto STAGE = [&](int c, int kt){
    #pragma unroll
    for (int i = 0; i < 2; ++i)
      gload_lds16(Ab + (size_t)(i * 16) * Kdim + kt * 32,
                  lds + c * 16384 + wid * 2048 + i * 1024);
    gload_lds16(Bb + kt * 32, lds + 32768 + c * 8192 + wid * 1024);
  };
  auto ldA = [&](int c, int mi) -> bf16x8 {
    int row = wid * 32 + mi * 16 + lrow;
    return *(const bf16x8*)(lds + c * 16384 + row * 64 + ((g8 ^ SW(row)) << 4));
  };
  auto ldB = [&](int c, int ni) -> bf16x8 {
    int row = ni * 16 + lrow;
    return *(const bf16x8*)(lds + 32768 + c * 8192 + row * 64 + ((g8 ^ SW(row)) << 4));
  };

  STAGE(0, 0);

  for (int kt = 0; kt < NKT2; ++kt){
    const int c = kt & 1;
    asm volatile("s_waitcnt vmcnt(0)" ::: "memory");
    __builtin_amdgcn_s_barrier();
    if (kt + 1 < NKT2) STAGE(c ^ 1, kt + 1);

    bf16x8 af[2], bfv[8];
    #pragma unroll
    for (int mi = 0; mi < 2; ++mi) af[mi] = ldA(c, mi);
    #pragma unroll
    for (int ni = 0; ni < 8; ++ni) bfv[ni] = ldB(c, ni);
    #pragma unroll
    for (int mi = 0; mi < 2; ++mi)
      #pragma unroll
      for (int ni = 0; ni < 8; ++ni)
        acc[mi][ni] = __builtin_amdgcn_mfma_f32_16x16x32_bf16(
            af[mi], bfv[ni], acc[mi][ni], 0, 0, 0);
  }

  const int tsel = by >> 4;           // 0=q, 1=k, 2=v (block-uniform)
  const int hh = by & 15;             // single head per tile
  if (tsel < 2){
    // ---- register-only fused centered-RMS + rope epilogue ----
    const float* gv = tsel ? gk : gq;
    const float* bv = tsel ? bk : bq;
    float gcoef[8], bcoef[8];
    #pragma unroll
    for (int ni = 0; ni < 8; ++ni){
      int d = ni * 16 + lrow;
      gcoef[ni] = 1.0f + gv[hh * 128 + d];
      bcoef[ni] = bv[hh * 128 + d];
    }
    const float qsc = tsel ? 1.0f : 0.011271055007f;   // log2(e)/128 on q
    short* dstn = Cn + (size_t)tsel * (NB * NH * NT * ND);
    #pragma unroll
    for (int mi = 0; mi < 2; ++mi)
      #pragma unroll
      for (int r = 0; r < 4; ++r){
        float s1 = 0.0f, s2 = 0.0f;
        #pragma unroll
        for (int ni = 0; ni < 8; ++ni){
          float v = acc[mi][ni][r];
          s1 += v; s2 += v * v;
        }
        #pragma unroll
        for (int off = 1; off < 16; off <<= 1){
          s1 += __shfl_xor(s1, off);
          s2 += __shfl_xor(s2, off);
        }
        float mean = s1 * (1.0f / 128.0f);
        float var = s2 * (1.0f / 128.0f) - mean * mean;
        float rstd = rsqrtf(var + 1e-6f);
        float nv[8];
        #pragma unroll
        for (int ni = 0; ni < 8; ++ni)
          nv[ni] = (acc[mi][ni][r] - mean) * rstd * gcoef[ni] + bcoef[ni];
        int rowb = m0 + wid * 32 + mi * 16 + g8 * 4 + r;
        int b = rowb >> 11, t = rowb & 2047;
        size_t rbase = (((size_t)(b * NH + hh)) * NT + t) * ND;
        #pragma unroll
        for (int lo = 0; lo < 4; ++lo){
          int dl = lo * 16 + lrow;
          float c = ctab[t * 64 + dl], sn = stab[t * 64 + dl];
          float oe = (nv[lo] * c - nv[lo + 4] * sn) * qsc;
          float oo = (nv[lo] * sn + nv[lo + 4] * c) * qsc;
          dstn[rbase + dl]      = (short)f2bf(oe);
          dstn[rbase + dl + 64] = (short)f2bf(oo);
        }
      }
  } else {
    // ---- V: tile-transposed bf16x4 stores ----
    #pragma unroll
    for (int mi = 0; mi < 2; ++mi){
      int rowb = m0 + wid * 32 + mi * 16 + g8 * 4;
      int b = rowb >> 11, t0 = rowb & 2047;
      int jb = t0 >> 6, toff = t0 & 63;
      #pragma unroll
      for (int ni = 0; ni < 8; ++ni){
        int d = ni * 16 + lrow;
        f32x4 a = acc[mi][ni];
        bf16x4 w4;
        #pragma unroll
        for (int r = 0; r < 4; ++r) w4[r] = (short)f2bf(a[r]);
        *(bf16x4*)&Cv[(((size_t)(b * NH + hh) * 32 + jb) * ND + d) * 64 + toff] = w4;
      }
    }
  }
}

// ---------------- out-proj GEMM v2: 256x128, BK=32, fp32 out ---------------
__global__ __launch_bounds__(512, 4) void gemmo_k(const short* __restrict__ A,
                                                  const short* __restrict__ Bt,
                                                  float* __restrict__ Cout){
  extern __shared__ char lds[];
  const int tid = threadIdx.x;
  const int wid = tid >> 6, lane = tid & 63;
  const int lrow = lane & 15, g8 = lane >> 4;
  const int wm = wid >> 1, wn = wid & 1;
  const int Kdim = 2048;

  int bid = blockIdx.x;
  int s = (bid & 7) * 32 + (bid >> 3);
  const int bx = s & 15;
  const int by = s >> 4;
  const int m0 = bx * 256, n0 = by * 128;

  const int ar = lane >> 2;
  const int ag = (lane & 3) ^ SW(ar);
  const short* Ab = A  + (size_t)(m0 + wid * 32 + ar) * Kdim + ag * 8;
  const short* Bb = Bt + (size_t)(n0 + wid * 16 + ar) * Kdim + ag * 8;

  f32x4 acc[4][4] = {};

  auto STAGE = [&](int c, int kt){
    #pragma unroll
    for (int i = 0; i < 2; ++i)
      gload_lds16(Ab + (size_t)(i * 16) * Kdim + kt * 32,
                  lds + c * 16384 + wid * 2048 + i * 1024);
    gload_lds16(Bb + kt * 32, lds + 32768 + c * 8192 + wid * 1024);
  };
  auto ldA = [&](int c, int mi) -> bf16x8 {
    int row = wm * 64 + mi * 16 + lrow;
    return *(const bf16x8*)(lds + c * 16384 + row * 64 + ((g8 ^ SW(row)) << 4));
  };
  auto ldB = [&](int c, int ni) -> bf16x8 {
    int row = wn * 64 + ni * 16 + lrow;
    return *(const bf16x8*)(lds + 32768 + c * 8192 + row * 64 + ((g8 ^ SW(row)) << 4));
  };

  STAGE(0, 0);

  for (int kt = 0; kt < NKT2; ++kt){
    const int c = kt & 1;
    asm volatile("s_waitcnt vmcnt(0)" ::: "memory");
    __builtin_amdgcn_s_barrier();
    if (kt + 1 < NKT2) STAGE(c ^ 1, kt + 1);

    bf16x8 af[4], bfv[4];
    #pragma unroll
    for (int mi = 0; mi < 4; ++mi) af[mi] = ldA(c, mi);
    #pragma unroll
    for (int ni = 0; ni < 4; ++ni) bfv[ni] = ldB(c, ni);
    #pragma unroll
    for (int mi = 0; mi < 4; ++mi)
      #pragma unroll
      for (int ni = 0; ni < 4; ++ni)
        acc[mi][ni] = __builtin_amdgcn_mfma_f32_16x16x32_bf16(
            af[mi], bfv[ni], acc[mi][ni], 0, 0, 0);
  }

  #pragma unroll
  for (int mi = 0; mi < 4; ++mi){
    int rowb = m0 + wm * 64 + mi * 16 + g8 * 4;
    #pragma unroll
    for (int ni = 0; ni < 4; ++ni){
      int col = n0 + wn * 64 + ni * 16 + lrow;
      f32x4 a = acc[mi][ni];
      #pragma unroll
      for (int r = 0; r < 4; ++r)
        Cout[(size_t)(rowb + r) * 2048 + col] = a[r];
    }
  }
}

// ---------------- flash attention v3: QBLK=128, 8 waves, triple-buffer -----
__global__ __launch_bounds__(512) void attn_k(const short* __restrict__ qn,
                                              const short* __restrict__ kn,
                                              const short* __restrict__ vt,
                                              short* __restrict__ ob){
  extern __shared__ char lds[];
  const int tid = threadIdx.x;
  const int wid = tid >> 6, lane = tid & 63;   // wid 0..7
  const int lrow = lane & 15, g8 = lane >> 4;
  const int id = blockIdx.x;
  const int qs = id >> 5;             // 0..7
  const int bh = id & 31;             // same-bh ids congruent mod 8 -> same XCD
  const int b = bh >> 4, h = bh & 15;
  const size_t base = (size_t)bh * NT * ND;
  char* Pw = lds + 98304 + wid * 2048;

  auto STAGE = [&](int jb){
    const int cb = jb % 3;
    #pragma unroll
    for (int i = 0; i < 2; ++i){
      int r0 = wid * 4 + i * 32;
      int r = r0 + (lane >> 4);
      int g = lane & 15;
      gload_lds16(kn + base + (size_t)(jb * 64 + r) * ND + ((g ^ (r & 7)) << 3),
                  lds + cb * 16384 + r0 * 256);
    }
    #pragma unroll
    for (int i = 0; i < 2; ++i){
      int d0 = wid * 8 + i * 64;
      int d = d0 + (lane >> 3);
      int g = lane & 7;
      gload_lds16(vt + base + (size_t)jb * 8192 + d * 64 + ((g ^ (d & 7)) << 3),
                  lds + 49152 + cb * 16384 + d0 * 128);
    }
  };

  for (int pass = 0; pass < 2; ++pass){
    const int qt = pass ? (15 - qs) : qs;      // supertile of 128 q-rows
    const int t0 = qt * 128;
    const int wrow0 = t0 + wid * 16;
    const int tq = wrow0 + lrow;
    bf16x8 qf[4];
    #pragma unroll
    for (int dc = 0; dc < 4; ++dc)
      qf[dc] = *(const bf16x8*)(qn + base + (size_t)tq * ND + dc * 32 + g8 * 8);
    f32x4 O[8] = {};
    float m = -3e38f, lsum = 0.0f;
    const int ntiles = 2 * qt + 2;

    __syncthreads();             // all reads of LDS from previous pass done
    STAGE(0);
    STAGE(1);

    for (int jb = 0; jb < ntiles; ++jb){
      if (jb + 1 < ntiles) asm volatile("s_waitcnt vmcnt(4)" ::: "memory");
      else                 asm volatile("s_waitcnt vmcnt(0)" ::: "memory");
      __builtin_amdgcn_s_barrier();          // tile jb resident
      if (jb + 2 < ntiles) STAGE(jb + 2);    // write buf (jb+2)%3: readers done
      const char* Kb = lds + (jb % 3) * 16384;
      const char* Vb = lds + 49152 + (jb % 3) * 16384;

      if (jb * 64 <= wrow0 + 15){
        f32x4 st[4] = {};
        __builtin_amdgcn_s_setprio(1);
        #pragma unroll
        for (int dc = 0; dc < 4; ++dc)
          #pragma unroll
          for (int js = 0; js < 4; ++js){
            int jl = js * 16 + lrow;
            bf16x8 kf = *(const bf16x8*)(Kb + jl * 256 +
                          (((dc * 4 + g8) ^ (jl & 7)) << 4));
            st[js] = __builtin_amdgcn_mfma_f32_16x16x32_bf16(kf, qf[dc], st[js], 0, 0, 0);
          }
        __builtin_amdgcn_s_setprio(0);
        if (jb * 64 + 63 > wrow0){
          #pragma unroll
          for (int js = 0; js < 4; ++js)
            #pragma unroll
            for (int r = 0; r < 4; ++r){
              int j = jb * 64 + js * 16 + g8 * 4 + r;
              if (j > tq) st[js][r] = -3e38f;
            }
        }
        f32x4 m4 = st[0];
        #pragma unroll
        for (int js = 1; js < 4; ++js)
          #pragma unroll
          for (int r = 0; r < 4; ++r) m4[r] = fmaxf(m4[r], st[js][r]);
        float mx = fmaxf(fmaxf(m4[0], m4[1]), fmaxf(m4[2], m4[3]));
        mx = fmaxf(mx, __shfl_xor(mx, 16));
        mx = fmaxf(mx, __shfl_xor(mx, 32));
        if (!__all(mx <= m + 8.0f)){
          float mnew = fmaxf(m, mx);
          float fac = exp2f(m - mnew);
          m = mnew;
          lsum *= fac;
          #pragma unroll
          for (int dcb = 0; dcb < 8; ++dcb) O[dcb] *= fac;
        }
        float ps = 0.0f;
        #pragma unroll
        for (int js = 0; js < 4; ++js){
          float p0 = exp2f(st[js][0] - m);
          float p1 = exp2f(st[js][1] - m);
          float p2 = exp2f(st[js][2] - m);
          float p3 = exp2f(st[js][3] - m);
          ps += (p0 + p1) + (p2 + p3);
          unsigned int lo, hi;
          asm("v_cvt_pk_bf16_f32 %0, %1, %2" : "=v"(lo) : "v"(p0), "v"(p1));
          asm("v_cvt_pk_bf16_f32 %0, %1, %2" : "=v"(hi) : "v"(p2), "v"(p3));
          uint2 w; w.x = lo; w.y = hi;
          *(uint2*)(Pw + lrow * 128 + ((js * 32 + g8 * 8) ^ ((lrow & 7) << 4))) = w;
        }
        ps += __shfl_xor(ps, 16);
        ps += __shfl_xor(ps, 32);
        lsum += ps;
        asm volatile("s_waitcnt lgkmcnt(0)" ::: "memory");
        __builtin_amdgcn_s_setprio(1);
        #pragma unroll
        for (int j32 = 0; j32 < 2; ++j32){
          bf16x8 pf = *(const bf16x8*)(Pw + lrow * 128 +
                        ((j32 * 64 + g8 * 16) ^ ((lrow & 7) << 4)));
          #pragma unroll
          for (int dcb = 0; dcb < 8; ++dcb){
            int d = dcb * 16 + lrow;
            bf16x8 vf = *(const bf16x8*)(Vb + d * 128 +
                          (((j32 * 4 + g8) ^ (d & 7)) << 4));
            O[dcb] = __builtin_amdgcn_mfma_f32_16x16x32_bf16(vf, pf, O[dcb], 0, 0, 0);
          }
        }
        __builtin_amdgcn_s_setprio(0);
      }
    }
    float inv = 1.0f / lsum;
    #pragma unroll
    for (int dcb = 0; dcb < 8; ++dcb){
      bf16x4 w4;
      #pragma unroll
      for (int r = 0; r < 4; ++r) w4[r] = (short)f2bf(O[dcb][r] * inv);
      *(bf16x4*)(ob + ((size_t)(b * NT + tq)) * (NH * ND) + h * ND + dcb * 16 + g8 * 4) = w4;
    }
  }
}

// ---------------------------------------------------------------------------
extern "C" void kernel_launch(void* const* d_in, const int* in_sizes, int n_in,
                              void* d_out, int out_size, void* d_ws, size_t ws_size,
                              hipStream_t stream){
  const float* x  = (const float*)d_in[0];
  const float* wq = (const float*)d_in[1];
  const float* wk = (const float*)d_in[2];
  const float* wv = (const float*)d_in[3];
  const float* wo = (const float*)d_in[4];
  const float* gq = (const float*)d_in[5];
  const float* bq = (const float*)d_in[6];
  const float* gk = (const float*)d_in[7];
  const float* bk = (const float*)d_in[8];

  char* ws = (char*)d_ws;
  short* xb   = (short*)(ws);                      // 16,777,216 B
  short* wT   = (short*)(ws + 16777216);           // 33,554,432 B (q,k,v,o ^T)
  short* qkvb = (short*)(ws + 50331648);           // 50,331,648 B (v^T region used)
  short* qkn  = (short*)(ws + 100663296);          // 33,554,432 B (qn|kn)
  short* ob   = (short*)(ws + 134217728);          // 16,777,216 B
  float* ctab = (float*)(ws + 150994944);          // 524,288 B
  float* stab = (float*)(ws + 151519232);          // 524,288 B

  (void)hipFuncSetAttribute((const void*)gemm256_k,
                            hipFuncAttributeMaxDynamicSharedMemorySize, 49152);
  (void)hipFuncSetAttribute((const void*)gemmo_k,
                            hipFuncAttributeMaxDynamicSharedMemorySize, 49152);
  (void)hipFuncSetAttribute((const void*)attn_k,
                            hipFuncAttributeMaxDynamicSharedMemorySize, 114688);

  prep_k<<<dim3(25088), dim3(256), 0, stream>>>(x, wq, wk, wv, wo, xb, wT, ctab, stab);
  gemm256_k<<<dim3(768), dim3(512), 49152, stream>>>(xb, wT,
                                                     qkvb + 2 * (size_t)8388608, qkn,
                                                     gq, bq, gk, bk, ctab, stab);
  attn_k<<<dim3(256), dim3(512), 114688, stream>>>(qkn, qkn + 8388608,
                                                   qkvb + 2 * (size_t)8388608, ob);
  gemmo_k<<<dim3(256), dim3(512), 49152, stream>>>(ob, wT + 3 * (size_t)4194304,
                                                   (float*)d_out);
}